// Round 5
// baseline (1007.949 us; speedup 1.0000x reference)
//
#include <hip/hip_runtime.h>
#include <hip/hip_bf16.h>

// ---------------------------------------------------------------------------
// Workspace layout (256 MiB):
//  [0,64MB)    : a_planar [b][cc64][f64][w128] bf16
//  [64,128MB)  : a_nhwc   [b][h64][w128][cc64] bf16  (w in [121,128) zeroed)
//  [128,192MB) : t_nhwc   [b][h64][w128][cc64] bf16  (w in [121,128) zeroed)
//  [192,256MB) : csum     [b][n32][h64][w121]  fp32  (60.5MB)
//                tail: AF (conv weight frags hi+lo, 720KB), WF (DFT frags,
//                32KB), BB (real-ified biases), wl2T (232KB)
//
// Real-ified complex conv: channels cc<32 = real, cc>=32 = imag.
// Wbig[o][cc]: o<32 (real out): [wr | -wi]; o>=32 (imag out): [wi | wr].
// All MFMA weights split-precision: part0 = bf16(w), part1 = bf16(w-part0).
// AF layout: [conv5][tap9][part2][ks2][mt4][lane64][j8] bf16.
// Conv kernel: NO LDS staging — B-fragments load straight from global NHWC
// (lane gets 16B of contiguous cc), L1/L2 serve the 3x tap + 3x h-neighbor
// reuse. Wave owns M-tiles {m, m+2} so each lane holds rows o and o+32
// (real+imag pair) -> csum epilogue is register-only (no LDS, no barriers).
// ---------------------------------------------------------------------------

typedef __attribute__((ext_vector_type(8))) short bf16x8;
typedef __attribute__((ext_vector_type(4))) short bf16x4;
typedef __attribute__((ext_vector_type(4))) float f32x4;

__device__ __forceinline__ ushort f2bf(float v) {
  __hip_bfloat16 h = __float2bfloat16(v);
  return *reinterpret_cast<ushort*>(&h);
}
__device__ __forceinline__ float bf2f_raw(ushort u) {
  union { uint i; float f; } c; c.i = ((uint)u) << 16; return c.f;
}
__device__ __forceinline__ void split_bf(float v, ushort& h, ushort& l) {
  h = f2bf(v); l = f2bf(v - bf2f_raw(h));
}
__device__ __forceinline__ bf16x8 mk8(bf16x4 a, bf16x4 b) {
  bf16x8 r;
  r[0]=a[0]; r[1]=a[1]; r[2]=a[2]; r[3]=a[3];
  r[4]=b[0]; r[5]=b[1]; r[6]=b[2]; r[7]=b[3];
  return r;
}

#define MFMA16(A,B,C) __builtin_amdgcn_mfma_f32_16x16x32_bf16(A, B, C, 0, 0, 0)
// split-precision product X*Y ~= Xh*Yh + Xl*Yh + Xh*Yl
#define SPMACC(acc, Ah, Al, Bh, Bl)      \
  acc = MFMA16(Ah, Bh, acc);             \
  acc = MFMA16(Al, Bh, acc);             \
  acc = MFMA16(Ah, Bl, acc);

// ---------------------------------------------------------------------------
// Kernel 1: fused STFT + QK^T + sigmoid + A, all via MFMA. Block = (b,n).
// ---------------------------------------------------------------------------
__global__ __launch_bounds__(512) void stft_mfma_k(const float* __restrict__ x,
                                                   const ushort* __restrict__ WF,
                                                   ushort* __restrict__ ap) {
  __shared__ __align__(16) char smem[133376];
  const int bid = blockIdx.x;
  const int b = bid >> 5, n = bid & 31;
  const int tid = threadIdx.x;
  ushort* xph = reinterpret_cast<ushort*>(smem + 131072);
  ushort* xpl = xph + 576;

  // ---- phase 0: reflect-padded signal, split hi/lo ----
  for (int i = tid; i < 576; i += 512) {
    float v = 0.f;
    if (i < 544) {
      int p = i - 32;
      if (p < 0) p = -p;
      if (p >= 480) p = 958 - p;
      v = x[(b * 480 + p) * 32 + n];
    }
    ushort h, l; split_bf(v, h, l);
    xph[i] = h; xpl[i] = l;
  }
  __syncthreads();

  const int wv = tid >> 6, lane = tid & 63;
  const int mt = wv >> 1, nth = wv & 1;
  const int l15 = lane & 15, l4 = lane >> 4;

  // ---- phase 1: DFT  s[f][k] = W'[f][t] @ frames[t][k], frames[t][k]=xp[4k+t]
  bf16x8 WA[2][2][2];  // [cs][part][ks]
#pragma unroll
  for (int cs = 0; cs < 2; ++cs)
#pragma unroll
    for (int part = 0; part < 2; ++part)
#pragma unroll
      for (int ks = 0; ks < 2; ++ks)
        WA[cs][part][ks] = *reinterpret_cast<const bf16x8*>(
            WF + (((cs * 2 + part) * 2 + ks) * 4 + mt) * 512 + lane * 8);

  f32x4 acc1[2][4];
#pragma unroll
  for (int cs = 0; cs < 2; ++cs)
#pragma unroll
    for (int nt = 0; nt < 4; ++nt) acc1[cs][nt] = (f32x4){0.f, 0.f, 0.f, 0.f};

#pragma unroll
  for (int ks = 0; ks < 2; ++ks) {
    bf16x8 bh[4], bl[4];
#pragma unroll
    for (int nt = 0; nt < 4; ++nt) {
      int n_ = ((nth * 4 + nt) * 16) + l15;      // frame index (N dim)
      int e = n_ * 4 + ks * 32 + l4 * 8;
      bf16x4 h0 = *reinterpret_cast<const bf16x4*>(xph + e);
      bf16x4 h1 = *reinterpret_cast<const bf16x4*>(xph + e + 4);
      bf16x4 l0 = *reinterpret_cast<const bf16x4*>(xpl + e);
      bf16x4 l1 = *reinterpret_cast<const bf16x4*>(xpl + e + 4);
      bh[nt] = mk8(h0, h1); bl[nt] = mk8(l0, l1);
    }
#pragma unroll
    for (int cs = 0; cs < 2; ++cs)
#pragma unroll
      for (int nt = 0; nt < 4; ++nt) {
        SPMACC(acc1[cs][nt], WA[cs][0][ks], WA[cs][1][ks], bh[nt], bl[nt]);
      }
  }

  // write s[f][k] (row 256B, swz ^(f&7)<<4) and sT[k][f] (row 128B, ^(k&7)<<4)
#pragma unroll
  for (int cs = 0; cs < 2; ++cs)
#pragma unroll
    for (int nt = 0; nt < 4; ++nt) {
      int k = (nth * 4 + nt) * 16 + l15;
      bool kv = (k < 121);
#pragma unroll
      for (int r = 0; r < 4; ++r) {
        int f = mt * 16 + l4 * 4 + r;
        float v = kv ? acc1[cs][nt][r] : 0.f;
        ushort h, l; split_bf(v, h, l);
        int ba = (f << 8) + (k << 1); ba ^= (f & 7) << 4;
        *reinterpret_cast<ushort*>(smem + cs * 32768 + ba) = h;
        *reinterpret_cast<ushort*>(smem + cs * 32768 + 16384 + ba) = l;
        int bt = (k << 7) + (f << 1); bt ^= (k & 7) << 4;
        *reinterpret_cast<ushort*>(smem + 65536 + cs * 32768 + bt) = h;
        *reinterpret_cast<ushort*>(smem + 65536 + cs * 32768 + 16384 + bt) = l;
      }
    }
  __syncthreads();

  // ---- phase 2: QK^T + sigmoid ----
  f32x4 acc2[2][4];  // [nt][rr, ii, ri, ir]
#pragma unroll
  for (int nt = 0; nt < 2; ++nt)
#pragma unroll
    for (int c = 0; c < 4; ++c) acc2[nt][c] = (f32x4){0.f, 0.f, 0.f, 0.f};

#pragma unroll
  for (int ks = 0; ks < 4; ++ks) {
    bf16x8 A_[2][2];  // [comp][part]
#pragma unroll
    for (int comp = 0; comp < 2; ++comp)
#pragma unroll
      for (int part = 0; part < 2; ++part) {
        int f = mt * 16 + l15;
        int ba = (f << 8) + ((ks * 32 + l4 * 8) << 1); ba ^= (f & 7) << 4;
        A_[comp][part] = *reinterpret_cast<const bf16x8*>(smem + comp * 32768 + part * 16384 + ba);
      }
    bf16x8 B_[2][2][2];  // [comp][part][nt]
#pragma unroll
    for (int comp = 0; comp < 2; ++comp)
#pragma unroll
      for (int part = 0; part < 2; ++part)
#pragma unroll
        for (int nt = 0; nt < 2; ++nt) {
          int g = (nth * 2 + nt) * 16 + l15;
          int ba = (g << 8) + ((ks * 32 + l4 * 8) << 1); ba ^= (g & 7) << 4;
          B_[comp][part][nt] = *reinterpret_cast<const bf16x8*>(smem + comp * 32768 + part * 16384 + ba);
        }
#pragma unroll
    for (int nt = 0; nt < 2; ++nt) {
      SPMACC(acc2[nt][0], A_[0][0], A_[0][1], B_[0][0][nt], B_[0][1][nt]);  // rr
      SPMACC(acc2[nt][1], A_[1][0], A_[1][1], B_[1][0][nt], B_[1][1][nt]);  // ii
      SPMACC(acc2[nt][2], A_[0][0], A_[0][1], B_[1][0][nt], B_[1][1][nt]);  // ri
      SPMACC(acc2[nt][3], A_[1][0], A_[1][1], B_[0][0][nt], B_[0][1][nt]);  // ir
    }
  }
  __syncthreads();  // all s reads done before Q overwrites s region

  // sigmoid + split -> Q planes: qrh@0 qrl@8K qih@16K qil@24K
#pragma unroll
  for (int nt = 0; nt < 2; ++nt) {
    int g = (nth * 2 + nt) * 16 + l15;
#pragma unroll
    for (int r = 0; r < 4; ++r) {
      int f = mt * 16 + l4 * 4 + r;
      float qr = acc2[nt][0][r] - acc2[nt][1][r];
      float qi = acc2[nt][2][r] + acc2[nt][3][r];
      float vr = 1.f / (1.f + __expf(-qr));
      float vi = 1.f / (1.f + __expf(-qi));
      int ba = (f << 7) + (g << 1); ba ^= (f & 7) << 4;
      ushort h, l;
      split_bf(vr, h, l);
      *reinterpret_cast<ushort*>(smem + ba) = h;
      *reinterpret_cast<ushort*>(smem + 8192 + ba) = l;
      split_bf(vi, h, l);
      *reinterpret_cast<ushort*>(smem + 16384 + ba) = h;
      *reinterpret_cast<ushort*>(smem + 24576 + ba) = l;
    }
  }
  __syncthreads();

  // ---- phase 3: A = Q @ S ----
  f32x4 acc3[4][3];  // [nt][Qr*sTr, Qi*sTi, ai]
#pragma unroll
  for (int nt = 0; nt < 4; ++nt)
#pragma unroll
    for (int c = 0; c < 3; ++c) acc3[nt][c] = (f32x4){0.f, 0.f, 0.f, 0.f};

#pragma unroll
  for (int ks = 0; ks < 2; ++ks) {
    bf16x8 QA[2][2];  // [comp][part]
#pragma unroll
    for (int comp = 0; comp < 2; ++comp)
#pragma unroll
      for (int part = 0; part < 2; ++part) {
        int f = mt * 16 + l15;
        int ba = (f << 7) + ((ks * 32 + l4 * 8) << 1); ba ^= (f & 7) << 4;
        QA[comp][part] = *reinterpret_cast<const bf16x8*>(smem + comp * 16384 + part * 8192 + ba);
      }
#pragma unroll
    for (int nt = 0; nt < 4; ++nt) {
      int k = (nth * 4 + nt) * 16 + l15;
      int bq = (k << 7) + ((ks * 32 + l4 * 8) << 1); bq ^= (k & 7) << 4;
      bf16x8 Srh = *reinterpret_cast<const bf16x8*>(smem + 65536 + bq);
      bf16x8 Srl = *reinterpret_cast<const bf16x8*>(smem + 81920 + bq);
      bf16x8 Sih = *reinterpret_cast<const bf16x8*>(smem + 98304 + bq);
      bf16x8 Sil = *reinterpret_cast<const bf16x8*>(smem + 114688 + bq);
      SPMACC(acc3[nt][0], QA[0][0], QA[0][1], Srh, Srl);
      SPMACC(acc3[nt][1], QA[1][0], QA[1][1], Sih, Sil);
      SPMACC(acc3[nt][2], QA[0][0], QA[0][1], Sih, Sil);
      SPMACC(acc3[nt][2], QA[1][0], QA[1][1], Srh, Srl);
    }
  }
  __syncthreads();

  // bounce: plane ar @0, ai @16K : [64 f][128 k] bf16, swz ^(f&7)<<4
#pragma unroll
  for (int nt = 0; nt < 4; ++nt) {
    int k = (nth * 4 + nt) * 16 + l15;
#pragma unroll
    for (int r = 0; r < 4; ++r) {
      int f = mt * 16 + l4 * 4 + r;
      float ar = acc3[nt][0][r] - acc3[nt][1][r];
      float ai = acc3[nt][2][r];
      int ba = (f << 8) + (k << 1); ba ^= (f & 7) << 4;
      *reinterpret_cast<ushort*>(smem + ba) = f2bf(ar);
      *reinterpret_cast<ushort*>(smem + 16384 + ba) = f2bf(ai);
    }
  }
  __syncthreads();

  uint4* dst = reinterpret_cast<uint4*>(ap);
  for (int i = tid; i < 2048; i += 512) {
    int comp = i >> 10, rem = i & 1023;
    int f = rem >> 4, q = rem & 15;
    uint4 v = *reinterpret_cast<const uint4*>(
        smem + comp * 16384 + (f << 8) + ((q ^ (f & 7)) << 4));
    dst[((size_t)(b * 64 + n + 32 * comp) * 64) * 16 + rem] = v;
  }
}

// ---------------------------------------------------------------------------
// Kernel 2: transpose a_planar [b][cc][h][w] -> a_nhwc [b][h][w][cc].
// ---------------------------------------------------------------------------
__global__ __launch_bounds__(256) void transpose_k(const ushort* __restrict__ ap,
                                                   ushort* __restrict__ an) {
  __shared__ ushort T[64 * 128];
  const int b = blockIdx.x >> 6, h = blockIdx.x & 63;
  const int tid = threadIdx.x;
#pragma unroll
  for (int it = 0; it < 4; ++it) {
    int i = it * 256 + tid;          // 1024 16B chunks
    int cc = i >> 4, q = i & 15;
    const uint4* src = reinterpret_cast<const uint4*>(ap) +
                       ((size_t)((b * 64 + cc) * 64 + h) * 16 + q);
    *reinterpret_cast<uint4*>(&T[cc * 128 + q * 8]) = *src;
  }
  __syncthreads();
  const int p = tid >> 1, cc0 = (tid & 1) * 32;
  uint ou[16];
#pragma unroll
  for (int it = 0; it < 16; ++it) {
    uint lo = T[(cc0 + 2 * it) * 128 + p];
    uint hi = T[(cc0 + 2 * it + 1) * 128 + p];
    ou[it] = lo | (hi << 16);
  }
  uint4* dst = reinterpret_cast<uint4*>(an + ((size_t)((b * 64 + h) * 128 + p) * 64 + cc0));
#pragma unroll
  for (int r = 0; r < 4; ++r) dst[r] = make_uint4(ou[4*r], ou[4*r+1], ou[4*r+2], ou[4*r+3]);
}

// ---------------------------------------------------------------------------
// Kernel 3: prep. blk<37: conv weight frags (split hi/lo) + biases.
//           blk==37: DFT matrix frags. blk==38: wl2 transpose.
// ---------------------------------------------------------------------------
__global__ __launch_bounds__(256) void prep_k(
    const float* __restrict__ w0r, const float* __restrict__ w0i,
    const float* __restrict__ b0r, const float* __restrict__ b0i,
    const float* __restrict__ W1r, const float* __restrict__ W1i,
    const float* __restrict__ B1r, const float* __restrict__ B1i,
    const float* __restrict__ W2r, const float* __restrict__ W2i,
    const float* __restrict__ B2r, const float* __restrict__ B2i,
    const float* __restrict__ wl2,
    ushort* __restrict__ AF, ushort* __restrict__ WF, float* __restrict__ BB,
    float* __restrict__ wl2T) {
  const int blk = blockIdx.x, tid = threadIdx.x;
  const float PI32 = 0.0981747704246810387f;  // pi/32

  if (blk == 38) {  // wl2T[k][t] = wl2[t][k]
    for (int i = tid; i < 121 * 480; i += 256) {
      int k = i / 480, t = i - k * 480;
      wl2T[i] = wl2[t * 121 + k];
    }
    return;
  }
  if (blk == 37) {  // DFT matrices: cs0 = win*cos/8, cs1 = -win*sin/8
    for (int i = tid; i < 16384; i += 256) {
      int j = i & 7, ln = (i >> 3) & 63, mt = (i >> 9) & 3, ks = (i >> 11) & 1;
      int part = (i >> 12) & 1, cs = (i >> 13) & 1;
      int f = mt * 16 + (ln & 15);
      int t = ks * 32 + (ln >> 4) * 8 + j;
      float win = 0.5f * (1.0f - __cosf(PI32 * (float)t));
      int m = (f * t) & 63;
      float sv, cv;
      __sincosf(PI32 * (float)m, &sv, &cv);
      float val = (cs == 0) ? (win * cv * 0.125f) : (-win * sv * 0.125f);
      ushort h = f2bf(val);
      WF[i] = part ? f2bf(val - bf2f_raw(h)) : h;
    }
    return;
  }

  int conv, tap, TT;
  const float *Wr, *Wi;
  if (blk == 0) { conv = 0; tap = 0; TT = 1; Wr = w0r; Wi = w0i; }
  else {
    int q = blk - 1; conv = 1 + q / 9; tap = q - (q / 9) * 9; TT = 9;
    if (conv == 1)      { Wr = W1r;        Wi = W1i; }
    else if (conv == 2) { Wr = W2r;        Wi = W2i; }
    else if (conv == 3) { Wr = W1r + 9216; Wi = W1i + 9216; }
    else                { Wr = W2r + 9216; Wi = W2i + 9216; }
  }
  ushort thi[16], tlo[16];
#pragma unroll
  for (int jj = 0; jj < 16; ++jj) {
    int e = tid * 16 + jj;
    int j = e & 7, lane_e = (e >> 3) & 63, mt = (e >> 9) & 3, ks = (e >> 11) & 1;
    int o  = mt * 16 + (lane_e & 15);
    int cc = ks * 32 + 8 * (lane_e >> 4) + j;
    int ci = cc & 31, ch = cc >> 5, on = o & 31, oh = o >> 5;
    float wr = Wr[(on * 32 + ci) * TT + tap];
    float wi = Wi[(on * 32 + ci) * TT + tap];
    float v = (oh == 0) ? (ch == 0 ? wr : -wi) : (ch == 0 ? wi : wr);
    ushort h = f2bf(v);
    thi[jj] = h;
    tlo[jj] = f2bf(v - bf2f_raw(h));
  }
  ushort* base = AF + conv * 73728 + tap * 8192 + tid * 16;
  uint4* dh = reinterpret_cast<uint4*>(base);
  uint4* dl = reinterpret_cast<uint4*>(base + 4096);
  dh[0] = *reinterpret_cast<uint4*>(&thi[0]);
  dh[1] = *reinterpret_cast<uint4*>(&thi[8]);
  dl[0] = *reinterpret_cast<uint4*>(&tlo[0]);
  dl[1] = *reinterpret_cast<uint4*>(&tlo[8]);

  if (blk == 0) {  // biases for all 5 convs
    for (int i = tid; i < 320; i += 256) {
      int c = i >> 6, o = i & 63;
      const float *br, *bi;
      if (c == 0)      { br = b0r;      bi = b0i; }
      else if (c == 1) { br = B1r;      bi = B1i; }
      else if (c == 2) { br = B2r;      bi = B2i; }
      else if (c == 3) { br = B1r + 32; bi = B1i + 32; }
      else             { br = B2r + 32; bi = B2i + 32; }
      BB[c * 64 + o] = (o < 32) ? (br[o] - bi[o]) : (br[o - 32] + bi[o - 32]);
    }
  }
}

// ---------------------------------------------------------------------------
// Kernel 4: MFMA implicit-GEMM conv, B direct from global (no staging).
// Block = (b,h) XCD-swizzled. Wave owns M-tiles {m, m+2} -> each lane holds
// output rows o and o+32 (real/imag pair). MODE 0/1: register-only epilogue,
// zero LDS, zero barriers. MODE 2: bf16 LDS bounce for the NHWC transpose.
// ---------------------------------------------------------------------------
template <int TAPS, int MODE>
__global__ __launch_bounds__(256) void conv_mfma_k(
    const ushort* __restrict__ xin, ushort* __restrict__ tout,
    const ushort* __restrict__ afrag, const float* __restrict__ bb,
    const float* __restrict__ wl0, float* __restrict__ csum, int d) {
  __shared__ ushort Lb[(MODE == 2) ? 64 * 132 : 64];
  const int wg = ((blockIdx.x & 7) << 9) | (blockIdx.x >> 3);
  const int b = wg >> 6, h = wg & 63;
  const int tid = threadIdx.x;
  const int wave = tid >> 6, lane = tid & 63;
  const int mtb = wave & 1;            // M-tiles {mtb, mtb+2}
  const int ntb = (wave >> 1) * 4;     // N-tiles {ntb..ntb+3}
  const int l15 = lane & 15, l4 = lane >> 4;
  const bf16x8 z8 = (bf16x8){0, 0, 0, 0, 0, 0, 0, 0};

  f32x4 acc[2][4];
#pragma unroll
  for (int mi = 0; mi < 2; ++mi)
#pragma unroll
    for (int nt = 0; nt < 4; ++nt) acc[mi][nt] = (f32x4){0.f, 0.f, 0.f, 0.f};

  const int ccoff = l4 * 8;            // lane's cc slice base within ks-half

#pragma unroll
  for (int tap = 0; tap < TAPS; ++tap) {
    const int dy = (TAPS == 1) ? 1 : (tap / 3);
    const int dx = (TAPS == 1) ? 1 : (tap - dy * 3);
    const int hh = (TAPS == 1) ? h : (h + (dy - 1) * d);
    if (TAPS > 1 && (hh < 0 || hh >= 64)) continue;   // zero rows: skip (A*0=0)
    const ushort* rowp = xin + ((size_t)(b * 64 + hh) << 13);
    const ushort* At = afrag + tap * 8192 + lane * 8;
#pragma unroll
    for (int ks = 0; ks < 2; ++ks) {
      bf16x8 bv[4];
#pragma unroll
      for (int nt = 0; nt < 4; ++nt) {
        int w = (ntb + nt) * 16 + l15 + (dx - 1) * d;
        bool val = ((unsigned)w < 128u);
        int wc = val ? w : 0;
        bf16x8 t = *reinterpret_cast<const bf16x8*>(rowp + wc * 64 + ks * 32 + ccoff);
        bv[nt] = val ? t : z8;
      }
      bf16x8 ah0 = *reinterpret_cast<const bf16x8*>(At + ks * 2048 + mtb * 512);
      bf16x8 ah1 = *reinterpret_cast<const bf16x8*>(At + ks * 2048 + (mtb + 2) * 512);
      bf16x8 al0 = *reinterpret_cast<const bf16x8*>(At + 4096 + ks * 2048 + mtb * 512);
      bf16x8 al1 = *reinterpret_cast<const bf16x8*>(At + 4096 + ks * 2048 + (mtb + 2) * 512);
#pragma unroll
      for (int nt = 0; nt < 4; ++nt) {
        acc[0][nt] = MFMA16(ah0, bv[nt], acc[0][nt]);
        acc[1][nt] = MFMA16(ah1, bv[nt], acc[1][nt]);
      }
#pragma unroll
      for (int nt = 0; nt < 4; ++nt) {
        acc[0][nt] = MFMA16(al0, bv[nt], acc[0][nt]);
        acc[1][nt] = MFMA16(al1, bv[nt], acc[1][nt]);
      }
    }
  }

  if constexpr (MODE == 2) {
    // bf16 LDS bounce -> NHWC store (pads w>=121 zeroed)
#pragma unroll
    for (int mi = 0; mi < 2; ++mi) {
#pragma unroll
      for (int r = 0; r < 4; ++r) {
        int o = (mtb + 2 * mi) * 16 + l4 * 4 + r;
        float bo = bb[o];
#pragma unroll
        for (int nt = 0; nt < 4; ++nt) {
          int w = (ntb + nt) * 16 + l15;
          Lb[o * 132 + w] = f2bf(acc[mi][nt][r] + bo);
        }
      }
    }
    __syncthreads();
    const int p = tid >> 1, cc0 = (tid & 1) * 32;
    const bool val = (p < 121);
    uint ou[16];
#pragma unroll
    for (int it = 0; it < 16; ++it) {
      uint lo = val ? Lb[(cc0 + 2 * it) * 132 + p] : 0u;
      uint hi = val ? Lb[(cc0 + 2 * it + 1) * 132 + p] : 0u;
      ou[it] = lo | (hi << 16);
    }
    uint4* dst = reinterpret_cast<uint4*>(tout + ((size_t)((b * 64 + h) * 128 + p) * 64 + cc0));
#pragma unroll
    for (int r = 0; r < 4; ++r) dst[r] = make_uint4(ou[4*r], ou[4*r+1], ou[4*r+2], ou[4*r+3]);
  } else {
    // register-only csum epilogue: lane holds rows o (real) and o+32 (imag)
    const float w00 = wl0[0], w01 = wl0[1];
    float br_[4], bi_[4];
#pragma unroll
    for (int r = 0; r < 4; ++r) {
      int n = mtb * 16 + l4 * 4 + r;
      br_[r] = bb[n]; bi_[r] = bb[n + 32];
    }
#pragma unroll
    for (int nt = 0; nt < 4; ++nt) {
      int w = (ntb + nt) * 16 + l15;
      if (w < 121) {
#pragma unroll
        for (int r = 0; r < 4; ++r) {
          int n = mtb * 16 + l4 * 4 + r;
          float rr = acc[0][nt][r] + br_[r];
          float im = acc[1][nt][r] + bi_[r];
          float v = (fmaxf(rr, 0.f) * w00 + fmaxf(im, 0.f) * w01) * (1.f / 3.f);
          float* p = csum + ((size_t)(b * 32 + n) * 64 + h) * 121 + w;
          if constexpr (MODE == 1) v += *p;
          *p = v;
        }
      }
    }
  }
}

// ---------------------------------------------------------------------------
// Kernel 5: epilogue. h[k] = mean_f(csum) + b_l0 ; y = h @ w_l2T + b_l2
// ---------------------------------------------------------------------------
__global__ __launch_bounds__(256) void epi_k(const float* __restrict__ csum,
    const float* __restrict__ bl0, const float* __restrict__ wl2T,
    const float* __restrict__ bl2, float* __restrict__ out) {
  const int b = blockIdx.x >> 5, n = blockIdx.x & 31;
  __shared__ float sh[121];
  const int tid = threadIdx.x;
  const float* base = csum + (size_t)(b * 32 + n) * 64 * 121;
  for (int k = tid; k < 121; k += 256) {
    float s = 0.f;
#pragma unroll 8
    for (int f = 0; f < 64; ++f) s += base[f * 121 + k];
    sh[k] = s * (1.f / 64.f) + bl0[0];
  }
  __syncthreads();
  for (int t = tid; t < 480; t += 256) {
    float acc = bl2[t];
#pragma unroll 8
    for (int k = 0; k < 121; ++k) acc = fmaf(sh[k], wl2T[k * 480 + t], acc);
    out[(b * 480 + t) * 32 + n] = acc;
  }
}

// ---------------------------------------------------------------------------
extern "C" void kernel_launch(void* const* d_in, const int* in_sizes, int n_in,
                              void* d_out, int out_size, void* d_ws, size_t ws_size,
                              hipStream_t stream) {
  const float* x   = (const float*)d_in[0];
  const float* w0r = (const float*)d_in[1];
  const float* w0i = (const float*)d_in[2];
  const float* b0r = (const float*)d_in[3];
  const float* b0i = (const float*)d_in[4];
  const float* W1r = (const float*)d_in[5];
  const float* W1i = (const float*)d_in[6];
  const float* B1r = (const float*)d_in[7];
  const float* B1i = (const float*)d_in[8];
  const float* W2r = (const float*)d_in[9];
  const float* W2i = (const float*)d_in[10];
  const float* B2r = (const float*)d_in[11];
  const float* B2i = (const float*)d_in[12];
  const float* wl0 = (const float*)d_in[13];
  const float* bl0 = (const float*)d_in[14];
  const float* wl2 = (const float*)d_in[15];
  const float* bl2 = (const float*)d_in[16];

  char* ws = (char*)d_ws;
  const size_t MB64 = (size_t)64 << 20;
  ushort* ap   = (ushort*)ws;                        // a_planar
  ushort* an   = (ushort*)(ws + MB64);               // a_nhwc
  ushort* tn   = (ushort*)(ws + 2 * MB64);           // t_nhwc
  float*  csum = (float*)(ws + 3 * MB64);            // [b][32][64][121] fp32
  const size_t CSZ = (size_t)64 * 32 * 64 * 121 * 4; // 63,438,848 B
  ushort* AF   = (ushort*)(ws + 3 * MB64 + CSZ);     // 737,280 B
  ushort* WFp  = AF + 5 * 73728;                     // 32,768 B
  float*  BB   = (float*)(WFp + 16384);              // 1,280 B
  float*  wl2T = BB + 320;                           // 232,320 B
  float*  out  = (float*)d_out;

  hipLaunchKernelGGL(prep_k, dim3(39), dim3(256), 0, stream,
                     w0r, w0i, b0r, b0i, W1r, W1i, B1r, B1i, W2r, W2i, B2r, B2i,
                     wl2, AF, WFp, BB, wl2T);
  hipLaunchKernelGGL(stft_mfma_k, dim3(2048), dim3(512), 0, stream, x, WFp, ap);
  hipLaunchKernelGGL(transpose_k, dim3(4096), dim3(256), 0, stream, ap, an);
  // conv0 (1x1) -> csum init
  hipLaunchKernelGGL((conv_mfma_k<1, 0>), dim3(4096), dim3(256), 0, stream,
                     an, (ushort*)nullptr, AF, BB, wl0, csum, 1);
  // pair k=1 (dilation 1)
  hipLaunchKernelGGL((conv_mfma_k<9, 2>), dim3(4096), dim3(256), 0, stream,
                     an, tn, AF + 1 * 73728, BB + 64, wl0, csum, 1);
  hipLaunchKernelGGL((conv_mfma_k<9, 1>), dim3(4096), dim3(256), 0, stream,
                     tn, (ushort*)nullptr, AF + 2 * 73728, BB + 128, wl0, csum, 1);
  // pair k=2 (dilation 2)
  hipLaunchKernelGGL((conv_mfma_k<9, 2>), dim3(4096), dim3(256), 0, stream,
                     an, tn, AF + 3 * 73728, BB + 192, wl0, csum, 2);
  hipLaunchKernelGGL((conv_mfma_k<9, 1>), dim3(4096), dim3(256), 0, stream,
                     tn, (ushort*)nullptr, AF + 4 * 73728, BB + 256, wl0, csum, 2);
  hipLaunchKernelGGL(epi_k, dim3(2048), dim3(256), 0, stream, csum, bl0, wl2T, bl2, out);
}

// Round 6
// 645.621 us; speedup vs baseline: 1.5612x; 1.5612x over previous
//
#include <hip/hip_runtime.h>
#include <hip/hip_bf16.h>

// ---------------------------------------------------------------------------
// Workspace layout (256 MiB):
//  [0,64MB)    : a_planar [b][cc64][f64][w128] bf16  -> reused as t2 after
//                transpose (conv1 d=2 output, NHWC)
//  [64,128MB)  : a_nhwc   [b][h64][w128][cc64] bf16  -> reused as csumB in D2
//  [128,192MB) : t1_nhwc  [b][h64][w128][cc64] bf16
//  [192,..)    : csumA    [b][n32][h64][w121]  fp32  (60.5MB)
//                tail: AF (conv weight frags hi+lo, 720KB), WF (DFT frags,
//                32KB), BB (real-ified biases), wl2T (232KB)
//
// Real-ified complex conv: channels cc<32 = real, cc>=32 = imag.
// Wbig[o][cc]: o<32 (real out): [wr | -wi]; o>=32 (imag out): [wi | wr].
// All MFMA weights split-precision: part0 = bf16(w), part1 = bf16(w-part0).
// AF layout: [conv5][tap9][part2][ks2][mt4][lane64][j8] bf16.
//
// Conv schedule (R6): per-dy row double-buffer in LDS (33.8KB -> 4 blocks/CU),
// reg-staged swizzled writes, next row's global loads issued before current
// row's compute (latency hidden). Dispatches merged for co-residency:
//  D1 (12288 blk): role bid%3: conv0->csumA | conv1 d1->t1 | conv1 d2->t2
//  D2 (8192 blk):  role bid&1: conv2 d1 +=csumA | conv2 d2 ->csumB (init)
// ---------------------------------------------------------------------------

typedef __attribute__((ext_vector_type(8))) short bf16x8;
typedef __attribute__((ext_vector_type(4))) short bf16x4;
typedef __attribute__((ext_vector_type(4))) float f32x4;

__device__ __forceinline__ ushort f2bf(float v) {
  __hip_bfloat16 h = __float2bfloat16(v);
  return *reinterpret_cast<ushort*>(&h);
}
__device__ __forceinline__ float bf2f_raw(ushort u) {
  union { uint i; float f; } c; c.i = ((uint)u) << 16; return c.f;
}
__device__ __forceinline__ void split_bf(float v, ushort& h, ushort& l) {
  h = f2bf(v); l = f2bf(v - bf2f_raw(h));
}
__device__ __forceinline__ bf16x8 mk8(bf16x4 a, bf16x4 b) {
  bf16x8 r;
  r[0]=a[0]; r[1]=a[1]; r[2]=a[2]; r[3]=a[3];
  r[4]=b[0]; r[5]=b[1]; r[6]=b[2]; r[7]=b[3];
  return r;
}

#define MFMA16(A,B,C) __builtin_amdgcn_mfma_f32_16x16x32_bf16(A, B, C, 0, 0, 0)
// split-precision product X*Y ~= Xh*Yh + Xl*Yh + Xh*Yl
#define SPMACC(acc, Ah, Al, Bh, Bl)      \
  acc = MFMA16(Ah, Bh, acc);             \
  acc = MFMA16(Al, Bh, acc);             \
  acc = MFMA16(Ah, Bl, acc);

// ---------------------------------------------------------------------------
// Kernel 1: fused STFT + QK^T + sigmoid + A, all via MFMA. Block = (b,n).
// ---------------------------------------------------------------------------
__global__ __launch_bounds__(512) void stft_mfma_k(const float* __restrict__ x,
                                                   const ushort* __restrict__ WF,
                                                   ushort* __restrict__ ap) {
  __shared__ __align__(16) char smem[133376];
  const int bid = blockIdx.x;
  const int b = bid >> 5, n = bid & 31;
  const int tid = threadIdx.x;
  ushort* xph = reinterpret_cast<ushort*>(smem + 131072);
  ushort* xpl = xph + 576;

  for (int i = tid; i < 576; i += 512) {
    float v = 0.f;
    if (i < 544) {
      int p = i - 32;
      if (p < 0) p = -p;
      if (p >= 480) p = 958 - p;
      v = x[(b * 480 + p) * 32 + n];
    }
    ushort h, l; split_bf(v, h, l);
    xph[i] = h; xpl[i] = l;
  }
  __syncthreads();

  const int wv = tid >> 6, lane = tid & 63;
  const int mt = wv >> 1, nth = wv & 1;
  const int l15 = lane & 15, l4 = lane >> 4;

  // ---- phase 1: DFT ----
  bf16x8 WA[2][2][2];  // [cs][part][ks]
#pragma unroll
  for (int cs = 0; cs < 2; ++cs)
#pragma unroll
    for (int part = 0; part < 2; ++part)
#pragma unroll
      for (int ks = 0; ks < 2; ++ks)
        WA[cs][part][ks] = *reinterpret_cast<const bf16x8*>(
            WF + (((cs * 2 + part) * 2 + ks) * 4 + mt) * 512 + lane * 8);

  f32x4 acc1[2][4];
#pragma unroll
  for (int cs = 0; cs < 2; ++cs)
#pragma unroll
    for (int nt = 0; nt < 4; ++nt) acc1[cs][nt] = (f32x4){0.f, 0.f, 0.f, 0.f};

#pragma unroll
  for (int ks = 0; ks < 2; ++ks) {
    bf16x8 bh[4], bl[4];
#pragma unroll
    for (int nt = 0; nt < 4; ++nt) {
      int n_ = ((nth * 4 + nt) * 16) + l15;
      int e = n_ * 4 + ks * 32 + l4 * 8;
      bf16x4 h0 = *reinterpret_cast<const bf16x4*>(xph + e);
      bf16x4 h1 = *reinterpret_cast<const bf16x4*>(xph + e + 4);
      bf16x4 l0 = *reinterpret_cast<const bf16x4*>(xpl + e);
      bf16x4 l1 = *reinterpret_cast<const bf16x4*>(xpl + e + 4);
      bh[nt] = mk8(h0, h1); bl[nt] = mk8(l0, l1);
    }
#pragma unroll
    for (int cs = 0; cs < 2; ++cs)
#pragma unroll
      for (int nt = 0; nt < 4; ++nt) {
        SPMACC(acc1[cs][nt], WA[cs][0][ks], WA[cs][1][ks], bh[nt], bl[nt]);
      }
  }

#pragma unroll
  for (int cs = 0; cs < 2; ++cs)
#pragma unroll
    for (int nt = 0; nt < 4; ++nt) {
      int k = (nth * 4 + nt) * 16 + l15;
      bool kv = (k < 121);
#pragma unroll
      for (int r = 0; r < 4; ++r) {
        int f = mt * 16 + l4 * 4 + r;
        float v = kv ? acc1[cs][nt][r] : 0.f;
        ushort h, l; split_bf(v, h, l);
        int ba = (f << 8) + (k << 1); ba ^= (f & 7) << 4;
        *reinterpret_cast<ushort*>(smem + cs * 32768 + ba) = h;
        *reinterpret_cast<ushort*>(smem + cs * 32768 + 16384 + ba) = l;
        int bt = (k << 7) + (f << 1); bt ^= (k & 7) << 4;
        *reinterpret_cast<ushort*>(smem + 65536 + cs * 32768 + bt) = h;
        *reinterpret_cast<ushort*>(smem + 65536 + cs * 32768 + 16384 + bt) = l;
      }
    }
  __syncthreads();

  // ---- phase 2: QK^T + sigmoid ----
  f32x4 acc2[2][4];  // [nt][rr, ii, ri, ir]
#pragma unroll
  for (int nt = 0; nt < 2; ++nt)
#pragma unroll
    for (int c = 0; c < 4; ++c) acc2[nt][c] = (f32x4){0.f, 0.f, 0.f, 0.f};

#pragma unroll
  for (int ks = 0; ks < 4; ++ks) {
    bf16x8 A_[2][2];
#pragma unroll
    for (int comp = 0; comp < 2; ++comp)
#pragma unroll
      for (int part = 0; part < 2; ++part) {
        int f = mt * 16 + l15;
        int ba = (f << 8) + ((ks * 32 + l4 * 8) << 1); ba ^= (f & 7) << 4;
        A_[comp][part] = *reinterpret_cast<const bf16x8*>(smem + comp * 32768 + part * 16384 + ba);
      }
    bf16x8 B_[2][2][2];
#pragma unroll
    for (int comp = 0; comp < 2; ++comp)
#pragma unroll
      for (int part = 0; part < 2; ++part)
#pragma unroll
        for (int nt = 0; nt < 2; ++nt) {
          int g = (nth * 2 + nt) * 16 + l15;
          int ba = (g << 8) + ((ks * 32 + l4 * 8) << 1); ba ^= (g & 7) << 4;
          B_[comp][part][nt] = *reinterpret_cast<const bf16x8*>(smem + comp * 32768 + part * 16384 + ba);
        }
#pragma unroll
    for (int nt = 0; nt < 2; ++nt) {
      SPMACC(acc2[nt][0], A_[0][0], A_[0][1], B_[0][0][nt], B_[0][1][nt]);
      SPMACC(acc2[nt][1], A_[1][0], A_[1][1], B_[1][0][nt], B_[1][1][nt]);
      SPMACC(acc2[nt][2], A_[0][0], A_[0][1], B_[1][0][nt], B_[1][1][nt]);
      SPMACC(acc2[nt][3], A_[1][0], A_[1][1], B_[0][0][nt], B_[0][1][nt]);
    }
  }
  __syncthreads();

#pragma unroll
  for (int nt = 0; nt < 2; ++nt) {
    int g = (nth * 2 + nt) * 16 + l15;
#pragma unroll
    for (int r = 0; r < 4; ++r) {
      int f = mt * 16 + l4 * 4 + r;
      float qr = acc2[nt][0][r] - acc2[nt][1][r];
      float qi = acc2[nt][2][r] + acc2[nt][3][r];
      float vr = 1.f / (1.f + __expf(-qr));
      float vi = 1.f / (1.f + __expf(-qi));
      int ba = (f << 7) + (g << 1); ba ^= (f & 7) << 4;
      ushort h, l;
      split_bf(vr, h, l);
      *reinterpret_cast<ushort*>(smem + ba) = h;
      *reinterpret_cast<ushort*>(smem + 8192 + ba) = l;
      split_bf(vi, h, l);
      *reinterpret_cast<ushort*>(smem + 16384 + ba) = h;
      *reinterpret_cast<ushort*>(smem + 24576 + ba) = l;
    }
  }
  __syncthreads();

  // ---- phase 3: A = Q @ S ----
  f32x4 acc3[4][3];
#pragma unroll
  for (int nt = 0; nt < 4; ++nt)
#pragma unroll
    for (int c = 0; c < 3; ++c) acc3[nt][c] = (f32x4){0.f, 0.f, 0.f, 0.f};

#pragma unroll
  for (int ks = 0; ks < 2; ++ks) {
    bf16x8 QA[2][2];
#pragma unroll
    for (int comp = 0; comp < 2; ++comp)
#pragma unroll
      for (int part = 0; part < 2; ++part) {
        int f = mt * 16 + l15;
        int ba = (f << 7) + ((ks * 32 + l4 * 8) << 1); ba ^= (f & 7) << 4;
        QA[comp][part] = *reinterpret_cast<const bf16x8*>(smem + comp * 16384 + part * 8192 + ba);
      }
#pragma unroll
    for (int nt = 0; nt < 4; ++nt) {
      int k = (nth * 4 + nt) * 16 + l15;
      int bq = (k << 7) + ((ks * 32 + l4 * 8) << 1); bq ^= (k & 7) << 4;
      bf16x8 Srh = *reinterpret_cast<const bf16x8*>(smem + 65536 + bq);
      bf16x8 Srl = *reinterpret_cast<const bf16x8*>(smem + 81920 + bq);
      bf16x8 Sih = *reinterpret_cast<const bf16x8*>(smem + 98304 + bq);
      bf16x8 Sil = *reinterpret_cast<const bf16x8*>(smem + 114688 + bq);
      SPMACC(acc3[nt][0], QA[0][0], QA[0][1], Srh, Srl);
      SPMACC(acc3[nt][1], QA[1][0], QA[1][1], Sih, Sil);
      SPMACC(acc3[nt][2], QA[0][0], QA[0][1], Sih, Sil);
      SPMACC(acc3[nt][2], QA[1][0], QA[1][1], Srh, Srl);
    }
  }
  __syncthreads();

#pragma unroll
  for (int nt = 0; nt < 4; ++nt) {
    int k = (nth * 4 + nt) * 16 + l15;
#pragma unroll
    for (int r = 0; r < 4; ++r) {
      int f = mt * 16 + l4 * 4 + r;
      float ar = acc3[nt][0][r] - acc3[nt][1][r];
      float ai = acc3[nt][2][r];
      int ba = (f << 8) + (k << 1); ba ^= (f & 7) << 4;
      *reinterpret_cast<ushort*>(smem + ba) = f2bf(ar);
      *reinterpret_cast<ushort*>(smem + 16384 + ba) = f2bf(ai);
    }
  }
  __syncthreads();

  uint4* dst = reinterpret_cast<uint4*>(ap);
  for (int i = tid; i < 2048; i += 512) {
    int comp = i >> 10, rem = i & 1023;
    int f = rem >> 4, q = rem & 15;
    uint4 v = *reinterpret_cast<const uint4*>(
        smem + comp * 16384 + (f << 8) + ((q ^ (f & 7)) << 4));
    dst[((size_t)(b * 64 + n + 32 * comp) * 64) * 16 + rem] = v;
  }
}

// ---------------------------------------------------------------------------
// Kernel 2: transpose a_planar [b][cc][h][w] -> a_nhwc [b][h][w][cc].
// ---------------------------------------------------------------------------
__global__ __launch_bounds__(256) void transpose_k(const ushort* __restrict__ ap,
                                                   ushort* __restrict__ an) {
  __shared__ ushort T[64 * 128];
  const int b = blockIdx.x >> 6, h = blockIdx.x & 63;
  const int tid = threadIdx.x;
#pragma unroll
  for (int it = 0; it < 4; ++it) {
    int i = it * 256 + tid;
    int cc = i >> 4, q = i & 15;
    const uint4* src = reinterpret_cast<const uint4*>(ap) +
                       ((size_t)((b * 64 + cc) * 64 + h) * 16 + q);
    *reinterpret_cast<uint4*>(&T[cc * 128 + q * 8]) = *src;
  }
  __syncthreads();
  const int p = tid >> 1, cc0 = (tid & 1) * 32;
  uint ou[16];
#pragma unroll
  for (int it = 0; it < 16; ++it) {
    uint lo = T[(cc0 + 2 * it) * 128 + p];
    uint hi = T[(cc0 + 2 * it + 1) * 128 + p];
    ou[it] = lo | (hi << 16);
  }
  uint4* dst = reinterpret_cast<uint4*>(an + ((size_t)((b * 64 + h) * 128 + p) * 64 + cc0));
#pragma unroll
  for (int r = 0; r < 4; ++r) dst[r] = make_uint4(ou[4*r], ou[4*r+1], ou[4*r+2], ou[4*r+3]);
}

// ---------------------------------------------------------------------------
// Kernel 3: prep (unchanged from R5).
// ---------------------------------------------------------------------------
__global__ __launch_bounds__(256) void prep_k(
    const float* __restrict__ w0r, const float* __restrict__ w0i,
    const float* __restrict__ b0r, const float* __restrict__ b0i,
    const float* __restrict__ W1r, const float* __restrict__ W1i,
    const float* __restrict__ B1r, const float* __restrict__ B1i,
    const float* __restrict__ W2r, const float* __restrict__ W2i,
    const float* __restrict__ B2r, const float* __restrict__ B2i,
    const float* __restrict__ wl2,
    ushort* __restrict__ AF, ushort* __restrict__ WF, float* __restrict__ BB,
    float* __restrict__ wl2T) {
  const int blk = blockIdx.x, tid = threadIdx.x;
  const float PI32 = 0.0981747704246810387f;

  if (blk == 38) {
    for (int i = tid; i < 121 * 480; i += 256) {
      int k = i / 480, t = i - k * 480;
      wl2T[i] = wl2[t * 121 + k];
    }
    return;
  }
  if (blk == 37) {
    for (int i = tid; i < 16384; i += 256) {
      int j = i & 7, ln = (i >> 3) & 63, mt = (i >> 9) & 3, ks = (i >> 11) & 1;
      int part = (i >> 12) & 1, cs = (i >> 13) & 1;
      int f = mt * 16 + (ln & 15);
      int t = ks * 32 + (ln >> 4) * 8 + j;
      float win = 0.5f * (1.0f - __cosf(PI32 * (float)t));
      int m = (f * t) & 63;
      float sv, cv;
      __sincosf(PI32 * (float)m, &sv, &cv);
      float val = (cs == 0) ? (win * cv * 0.125f) : (-win * sv * 0.125f);
      ushort h = f2bf(val);
      WF[i] = part ? f2bf(val - bf2f_raw(h)) : h;
    }
    return;
  }

  int conv, tap, TT;
  const float *Wr, *Wi;
  if (blk == 0) { conv = 0; tap = 0; TT = 1; Wr = w0r; Wi = w0i; }
  else {
    int q = blk - 1; conv = 1 + q / 9; tap = q - (q / 9) * 9; TT = 9;
    if (conv == 1)      { Wr = W1r;        Wi = W1i; }
    else if (conv == 2) { Wr = W2r;        Wi = W2i; }
    else if (conv == 3) { Wr = W1r + 9216; Wi = W1i + 9216; }
    else                { Wr = W2r + 9216; Wi = W2i + 9216; }
  }
  ushort thi[16], tlo[16];
#pragma unroll
  for (int jj = 0; jj < 16; ++jj) {
    int e = tid * 16 + jj;
    int j = e & 7, lane_e = (e >> 3) & 63, mt = (e >> 9) & 3, ks = (e >> 11) & 1;
    int o  = mt * 16 + (lane_e & 15);
    int cc = ks * 32 + 8 * (lane_e >> 4) + j;
    int ci = cc & 31, ch = cc >> 5, on = o & 31, oh = o >> 5;
    float wr = Wr[(on * 32 + ci) * TT + tap];
    float wi = Wi[(on * 32 + ci) * TT + tap];
    float v = (oh == 0) ? (ch == 0 ? wr : -wi) : (ch == 0 ? wi : wr);
    ushort h = f2bf(v);
    thi[jj] = h;
    tlo[jj] = f2bf(v - bf2f_raw(h));
  }
  ushort* base = AF + conv * 73728 + tap * 8192 + tid * 16;
  uint4* dh = reinterpret_cast<uint4*>(base);
  uint4* dl = reinterpret_cast<uint4*>(base + 4096);
  dh[0] = *reinterpret_cast<uint4*>(&thi[0]);
  dh[1] = *reinterpret_cast<uint4*>(&thi[8]);
  dl[0] = *reinterpret_cast<uint4*>(&tlo[0]);
  dl[1] = *reinterpret_cast<uint4*>(&tlo[8]);

  if (blk == 0) {
    for (int i = tid; i < 320; i += 256) {
      int c = i >> 6, o = i & 63;
      const float *br, *bi;
      if (c == 0)      { br = b0r;      bi = b0i; }
      else if (c == 1) { br = B1r;      bi = B1i; }
      else if (c == 2) { br = B2r;      bi = B2i; }
      else if (c == 3) { br = B1r + 32; bi = B1i + 32; }
      else             { br = B2r + 32; bi = B2i + 32; }
      BB[c * 64 + o] = (o < 32) ? (br[o] - bi[o]) : (br[o - 32] + bi[o - 32]);
    }
  }
}

// ---------------------------------------------------------------------------
// Conv building blocks.
// LDS per block: 2 row buffers, each [132 wp][64 cc] bf16 = 16896 B,
// swizzle byte ^= (wp&7)<<4. Total 33792 B -> 4 blocks/CU.
// ---------------------------------------------------------------------------
#define RPB 16896

__device__ __forceinline__ void conv_tap(const char* smem, int bufbase,
    const ushort* At, int dxoff, int ntb, int mtb, int l15, int l4,
    f32x4 acc[2][4]) {
#pragma unroll
  for (int ks = 0; ks < 2; ++ks) {
    bf16x8 bv[4];
#pragma unroll
    for (int nt = 0; nt < 4; ++nt) {
      int wp = (ntb + nt) * 16 + l15 + dxoff;
      int byt = bufbase + wp * 128 + ks * 64 + l4 * 16;
      byt ^= (wp & 7) << 4;
      bv[nt] = *reinterpret_cast<const bf16x8*>(smem + byt);
    }
    bf16x8 ah0 = *reinterpret_cast<const bf16x8*>(At + ks * 2048 + mtb * 512);
    bf16x8 ah1 = *reinterpret_cast<const bf16x8*>(At + ks * 2048 + (mtb + 2) * 512);
    bf16x8 al0 = *reinterpret_cast<const bf16x8*>(At + 4096 + ks * 2048 + mtb * 512);
    bf16x8 al1 = *reinterpret_cast<const bf16x8*>(At + 4096 + ks * 2048 + (mtb + 2) * 512);
#pragma unroll
    for (int nt = 0; nt < 4; ++nt) {
      acc[0][nt] = MFMA16(ah0, bv[nt], acc[0][nt]);
      acc[1][nt] = MFMA16(ah1, bv[nt], acc[1][nt]);
    }
#pragma unroll
    for (int nt = 0; nt < 4; ++nt) {
      acc[0][nt] = MFMA16(al0, bv[nt], acc[0][nt]);
      acc[1][nt] = MFMA16(al1, bv[nt], acc[1][nt]);
    }
  }
}

// ROWS = 1 (1x1 conv) or 3 (3x3 dilated). mode: 0 csum init, 1 csum add,
// 2 store t (NHWC, pads zeroed).
template <int ROWS>
__device__ __forceinline__ void conv_body(char* smem, const ushort* __restrict__ xin,
    ushort* __restrict__ tout, const ushort* __restrict__ afrag,
    const float* __restrict__ bb, const float* __restrict__ wl0,
    float* __restrict__ csum, int d, int b, int h, int mode, int tid) {
  const int wave = tid >> 6, lane = tid & 63;
  const int mtb = wave & 1;            // M-tiles {mtb, mtb+2} -> rows o, o+32
  const int ntb = (wave >> 1) * 4;
  const int l15 = lane & 15, l4 = lane >> 4;
  const uint4 z4 = make_uint4(0u, 0u, 0u, 0u);

  // zero border wp {0,1,130,131} in both buffers (never overwritten by rows)
  {
    const int nb = (ROWS == 3) ? 64 : 32;
    if (tid < nb) {
      int buf = tid >> 5, idx = tid & 31;
      int bi2 = idx >> 3, q = idx & 7;
      int wp = (bi2 < 2) ? bi2 : (128 + bi2);
      int byt = buf * RPB + wp * 128 + q * 16;
      byt ^= (wp & 7) << 4;
      *reinterpret_cast<uint4*>(smem + byt) = z4;
    }
  }

  uint4 st[4];
#define LOADROW(hh)                                                            \
  {                                                                            \
    const uint4* src = reinterpret_cast<const uint4*>(xin) +                   \
                       ((size_t)(b * 64 + (hh)) << 10);                        \
    st[0] = src[tid]; st[1] = src[tid + 256];                                  \
    st[2] = src[tid + 512]; st[3] = src[tid + 768];                            \
  }
#define WRITEROW(buf)                                                          \
  {                                                                            \
    _Pragma("unroll")                                                          \
    for (int it = 0; it < 4; ++it) {                                           \
      int i = it * 256 + tid;                                                  \
      int wp = (i >> 3) + 2, q = i & 7;                                        \
      int byt = (buf) * RPB + wp * 128 + q * 16;                               \
      byt ^= (wp & 7) << 4;                                                    \
      *reinterpret_cast<uint4*>(smem + byt) = st[it];                          \
    }                                                                          \
  }

  f32x4 acc[2][4];
#pragma unroll
  for (int mi = 0; mi < 2; ++mi)
#pragma unroll
    for (int nt = 0; nt < 4; ++nt) acc[mi][nt] = (f32x4){0.f, 0.f, 0.f, 0.f};

  if constexpr (ROWS == 1) {
    LOADROW(h);
    WRITEROW(0);
    __syncthreads();
    conv_tap(smem, 0, afrag + lane * 8, 2, ntb, mtb, l15, l4, acc);
  } else {
    const int hm = h - d, hp = h + d;
    const bool v0 = (hm >= 0), v2 = (hp < 64);
    if (v0) { LOADROW(hm); WRITEROW(0); }
    LOADROW(h);
    WRITEROW(1);
    if (v2) LOADROW(hp);          // in flight across the barrier + compute
    __syncthreads();
    if (v0) {
#pragma unroll
      for (int dx = 0; dx < 3; ++dx)
        conv_tap(smem, 0, afrag + (0 * 3 + dx) * 8192 + lane * 8,
                 (dx - 1) * d + 2, ntb, mtb, l15, l4, acc);
    }
#pragma unroll
    for (int dx = 0; dx < 3; ++dx)
      conv_tap(smem, RPB, afrag + (1 * 3 + dx) * 8192 + lane * 8,
               (dx - 1) * d + 2, ntb, mtb, l15, l4, acc);
    if (v2) {
      __syncthreads();            // all waves done reading buf0
      WRITEROW(0);
      __syncthreads();
#pragma unroll
      for (int dx = 0; dx < 3; ++dx)
        conv_tap(smem, 0, afrag + (2 * 3 + dx) * 8192 + lane * 8,
                 (dx - 1) * d + 2, ntb, mtb, l15, l4, acc);
    }
  }
#undef LOADROW
#undef WRITEROW

  if (mode == 2) {
    __syncthreads();
    ushort* Lb = reinterpret_cast<ushort*>(smem);   // [64][132]
#pragma unroll
    for (int mi = 0; mi < 2; ++mi) {
#pragma unroll
      for (int r = 0; r < 4; ++r) {
        int o = (mtb + 2 * mi) * 16 + l4 * 4 + r;
        float bo = bb[o];
#pragma unroll
        for (int nt = 0; nt < 4; ++nt) {
          int w = (ntb + nt) * 16 + l15;
          Lb[o * 132 + w] = f2bf(acc[mi][nt][r] + bo);
        }
      }
    }
    __syncthreads();
    const int p = tid >> 1, cc0 = (tid & 1) * 32;
    const bool val = (p < 121);
    uint ou[16];
#pragma unroll
    for (int it = 0; it < 16; ++it) {
      uint lo = val ? Lb[(cc0 + 2 * it) * 132 + p] : 0u;
      uint hi = val ? Lb[(cc0 + 2 * it + 1) * 132 + p] : 0u;
      ou[it] = lo | (hi << 16);
    }
    uint4* dst = reinterpret_cast<uint4*>(tout + ((size_t)((b * 64 + h) * 128 + p) * 64 + cc0));
#pragma unroll
    for (int r = 0; r < 4; ++r) dst[r] = make_uint4(ou[4*r], ou[4*r+1], ou[4*r+2], ou[4*r+3]);
  } else {
    const float w00 = wl0[0], w01 = wl0[1];
    float br_[4], bi_[4];
#pragma unroll
    for (int r = 0; r < 4; ++r) {
      int n = mtb * 16 + l4 * 4 + r;
      br_[r] = bb[n]; bi_[r] = bb[n + 32];
    }
#pragma unroll
    for (int nt = 0; nt < 4; ++nt) {
      int w = (ntb + nt) * 16 + l15;
      if (w < 121) {
#pragma unroll
        for (int r = 0; r < 4; ++r) {
          int n = mtb * 16 + l4 * 4 + r;
          float rr = acc[0][nt][r] + br_[r];
          float im = acc[1][nt][r] + bi_[r];
          float v = (fmaxf(rr, 0.f) * w00 + fmaxf(im, 0.f) * w01) * (1.f / 3.f);
          float* p = csum + ((size_t)(b * 32 + n) * 64 + h) * 121 + w;
          if (mode == 1) v += *p;
          *p = v;
        }
      }
    }
  }
}

// D1: role bid%3 -> conv0(an->csumA init) | conv1 d1(an->t1) | conv1 d2(an->t2)
__global__ __launch_bounds__(256) void convD1_k(
    const ushort* __restrict__ an, ushort* __restrict__ t1, ushort* __restrict__ t2,
    const ushort* __restrict__ AF, const float* __restrict__ BB,
    const float* __restrict__ wl0, float* __restrict__ csumA) {
  __shared__ __align__(16) char smem[2 * RPB];
  const int bid = blockIdx.x;
  const int role = bid % 3, sub = bid / 3;
  const int wg = ((sub & 7) << 9) | (sub >> 3);   // XCD-contiguous
  const int b = wg >> 6, h = wg & 63;
  const int tid = threadIdx.x;
  if (role == 0)
    conv_body<1>(smem, an, nullptr, AF, BB, wl0, csumA, 1, b, h, 0, tid);
  else if (role == 1)
    conv_body<3>(smem, an, t1, AF + 1 * 73728, BB + 64, wl0, nullptr, 1, b, h, 2, tid);
  else
    conv_body<3>(smem, an, t2, AF + 3 * 73728, BB + 192, wl0, nullptr, 2, b, h, 2, tid);
}

// D2: role bid&1 -> conv2 d1(t1 -> csumA add) | conv2 d2(t2 -> csumB init)
__global__ __launch_bounds__(256) void convD2_k(
    const ushort* __restrict__ t1, const ushort* __restrict__ t2,
    const ushort* __restrict__ AF, const float* __restrict__ BB,
    const float* __restrict__ wl0, float* __restrict__ csumA,
    float* __restrict__ csumB) {
  __shared__ __align__(16) char smem[2 * RPB];
  const int bid = blockIdx.x;
  const int role = bid & 1, sub = bid >> 1;
  const int wg = ((sub & 7) << 9) | (sub >> 3);
  const int b = wg >> 6, h = wg & 63;
  const int tid = threadIdx.x;
  if (role == 0)
    conv_body<3>(smem, t1, nullptr, AF + 2 * 73728, BB + 128, wl0, csumA, 1, b, h, 1, tid);
  else
    conv_body<3>(smem, t2, nullptr, AF + 4 * 73728, BB + 256, wl0, csumB, 2, b, h, 0, tid);
}

// ---------------------------------------------------------------------------
// Kernel 5: epilogue. h[k] = mean_f(csumA+csumB) + b_l0 ; y = h @ w_l2T + b_l2
// ---------------------------------------------------------------------------
__global__ __launch_bounds__(256) void epi_k(const float* __restrict__ csumA,
    const float* __restrict__ csumB,
    const float* __restrict__ bl0, const float* __restrict__ wl2T,
    const float* __restrict__ bl2, float* __restrict__ out) {
  const int b = blockIdx.x >> 5, n = blockIdx.x & 31;
  __shared__ float sh[121];
  const int tid = threadIdx.x;
  const float* baseA = csumA + (size_t)(b * 32 + n) * 64 * 121;
  const float* baseB = csumB + (size_t)(b * 32 + n) * 64 * 121;
  for (int k = tid; k < 121; k += 256) {
    float s = 0.f;
#pragma unroll 8
    for (int f = 0; f < 64; ++f) s += baseA[f * 121 + k] + baseB[f * 121 + k];
    sh[k] = s * (1.f / 64.f) + bl0[0];
  }
  __syncthreads();
  for (int t = tid; t < 480; t += 256) {
    float acc = bl2[t];
#pragma unroll 8
    for (int k = 0; k < 121; ++k) acc = fmaf(sh[k], wl2T[k * 480 + t], acc);
    out[(b * 480 + t) * 32 + n] = acc;
  }
}

// ---------------------------------------------------------------------------
extern "C" void kernel_launch(void* const* d_in, const int* in_sizes, int n_in,
                              void* d_out, int out_size, void* d_ws, size_t ws_size,
                              hipStream_t stream) {
  const float* x   = (const float*)d_in[0];
  const float* w0r = (const float*)d_in[1];
  const float* w0i = (const float*)d_in[2];
  const float* b0r = (const float*)d_in[3];
  const float* b0i = (const float*)d_in[4];
  const float* W1r = (const float*)d_in[5];
  const float* W1i = (const float*)d_in[6];
  const float* B1r = (const float*)d_in[7];
  const float* B1i = (const float*)d_in[8];
  const float* W2r = (const float*)d_in[9];
  const float* W2i = (const float*)d_in[10];
  const float* B2r = (const float*)d_in[11];
  const float* B2i = (const float*)d_in[12];
  const float* wl0 = (const float*)d_in[13];
  const float* bl0 = (const float*)d_in[14];
  const float* wl2 = (const float*)d_in[15];
  const float* bl2 = (const float*)d_in[16];

  char* ws = (char*)d_ws;
  const size_t MB64 = (size_t)64 << 20;
  ushort* ap    = (ushort*)ws;                       // a_planar -> t2 later
  ushort* t2    = (ushort*)ws;
  ushort* an    = (ushort*)(ws + MB64);              // a_nhwc -> csumB later
  float*  csumB = (float*)(ws + MB64);
  ushort* t1    = (ushort*)(ws + 2 * MB64);
  float*  csumA = (float*)(ws + 3 * MB64);           // [b][32][64][121] fp32
  const size_t CSZ = (size_t)64 * 32 * 64 * 121 * 4; // 63,438,848 B
  ushort* AF   = (ushort*)(ws + 3 * MB64 + CSZ);     // 737,280 B
  ushort* WFp  = AF + 5 * 73728;                     // 32,768 B
  float*  BB   = (float*)(WFp + 16384);              // 1,280 B
  float*  wl2T = BB + 320;                           // 232,320 B
  float*  out  = (float*)d_out;

  hipLaunchKernelGGL(prep_k, dim3(39), dim3(256), 0, stream,
                     w0r, w0i, b0r, b0i, W1r, W1i, B1r, B1i, W2r, W2i, B2r, B2i,
                     wl2, AF, WFp, BB, wl2T);
  hipLaunchKernelGGL(stft_mfma_k, dim3(2048), dim3(512), 0, stream, x, WFp, ap);
  hipLaunchKernelGGL(transpose_k, dim3(4096), dim3(256), 0, stream, ap, an);
  // D1: conv0 -> csumA ; conv1(d=1) -> t1 ; conv1(d=2) -> t2 (overwrites ap)
  hipLaunchKernelGGL(convD1_k, dim3(12288), dim3(256), 0, stream,
                     an, t1, t2, AF, BB, wl0, csumA);
  // D2: conv2(d=1) += csumA ; conv2(d=2) -> csumB (overwrites an)
  hipLaunchKernelGGL(convD2_k, dim3(8192), dim3(256), 0, stream,
                     t1, t2, AF, BB, wl0, csumA, csumB);
  hipLaunchKernelGGL(epi_k, dim3(2048), dim3(256), 0, stream,
                     csumA, csumB, bl0, wl2T, bl2, out);
}

// Round 7
// 638.586 us; speedup vs baseline: 1.5784x; 1.0110x over previous
//
#include <hip/hip_runtime.h>
#include <hip/hip_bf16.h>

// ---------------------------------------------------------------------------
// Workspace layout (256 MiB):
//  [0,64MB)    : a_planar [b][cc64][f64][w128] bf16  -> reused as t2 (NHWC)
//  [64,128MB)  : a_nhwc   [b][h64][w128][cc64] bf16  -> reused as csumB in D2
//  [128,192MB) : t1_nhwc  [b][h64][w128][cc64] bf16
//  [192,..)    : csumA    [b][n32][h64][w121]  fp32  (60.5MB)
//                tail: AF (conv weight frags hi+lo, 720KB), WF (32KB),
//                BB (biases), wl2T (232KB)
//
// Real-ified complex conv: channels cc<32 = real, cc>=32 = imag.
// Wbig[o][cc]: o<32 (real out): [wr | -wi]; o>=32 (imag out): [wi | wr].
// All MFMA weights split-precision: part0 = bf16(w), part1 = bf16(w-part0).
// AF layout: [conv5][tap9][part2][ks2][mt4][lane64][j8] bf16.
//
// Conv schedule (R7): 3 static LDS row buffers (48KB, 3 blocks/CU, 1 barrier),
// ping-pong A-frag register pipeline (hi/lo groups prefetched one part ahead),
// XCD mapping puts all roles of one (b,h) on the SAME XCD back-to-back.
//  D1 (12288 blk): x=bid&7,j=bid>>3: role=j%3: conv0->csumA | c1d1->t1 | c1d2->t2
//  D2 (8192 blk):  x=bid&7,j=bid>>3: role=j&1: c2d1 +=csumA | c2d2 ->csumB
// ---------------------------------------------------------------------------

typedef __attribute__((ext_vector_type(8))) short bf16x8;
typedef __attribute__((ext_vector_type(4))) short bf16x4;
typedef __attribute__((ext_vector_type(4))) float f32x4;

__device__ __forceinline__ ushort f2bf(float v) {
  __hip_bfloat16 h = __float2bfloat16(v);
  return *reinterpret_cast<ushort*>(&h);
}
__device__ __forceinline__ float bf2f_raw(ushort u) {
  union { uint i; float f; } c; c.i = ((uint)u) << 16; return c.f;
}
__device__ __forceinline__ void split_bf(float v, ushort& h, ushort& l) {
  h = f2bf(v); l = f2bf(v - bf2f_raw(h));
}
__device__ __forceinline__ bf16x8 mk8(bf16x4 a, bf16x4 b) {
  bf16x8 r;
  r[0]=a[0]; r[1]=a[1]; r[2]=a[2]; r[3]=a[3];
  r[4]=b[0]; r[5]=b[1]; r[6]=b[2]; r[7]=b[3];
  return r;
}

#define MFMA16(A,B,C) __builtin_amdgcn_mfma_f32_16x16x32_bf16(A, B, C, 0, 0, 0)
#define SPMACC(acc, Ah, Al, Bh, Bl)      \
  acc = MFMA16(Ah, Bh, acc);             \
  acc = MFMA16(Al, Bh, acc);             \
  acc = MFMA16(Ah, Bl, acc);

// ---------------------------------------------------------------------------
// Kernel 1: fused STFT + QK^T + sigmoid + A, all via MFMA. Block = (b,n).
// ---------------------------------------------------------------------------
__global__ __launch_bounds__(512) void stft_mfma_k(const float* __restrict__ x,
                                                   const ushort* __restrict__ WF,
                                                   ushort* __restrict__ ap) {
  __shared__ __align__(16) char smem[133376];
  const int bid = blockIdx.x;
  const int b = bid >> 5, n = bid & 31;
  const int tid = threadIdx.x;
  ushort* xph = reinterpret_cast<ushort*>(smem + 131072);
  ushort* xpl = xph + 576;

  for (int i = tid; i < 576; i += 512) {
    float v = 0.f;
    if (i < 544) {
      int p = i - 32;
      if (p < 0) p = -p;
      if (p >= 480) p = 958 - p;
      v = x[(b * 480 + p) * 32 + n];
    }
    ushort h, l; split_bf(v, h, l);
    xph[i] = h; xpl[i] = l;
  }
  __syncthreads();

  const int wv = tid >> 6, lane = tid & 63;
  const int mt = wv >> 1, nth = wv & 1;
  const int l15 = lane & 15, l4 = lane >> 4;

  // ---- phase 1: DFT ----
  bf16x8 WA[2][2][2];  // [cs][part][ks]
#pragma unroll
  for (int cs = 0; cs < 2; ++cs)
#pragma unroll
    for (int part = 0; part < 2; ++part)
#pragma unroll
      for (int ks = 0; ks < 2; ++ks)
        WA[cs][part][ks] = *reinterpret_cast<const bf16x8*>(
            WF + (((cs * 2 + part) * 2 + ks) * 4 + mt) * 512 + lane * 8);

  f32x4 acc1[2][4];
#pragma unroll
  for (int cs = 0; cs < 2; ++cs)
#pragma unroll
    for (int nt = 0; nt < 4; ++nt) acc1[cs][nt] = (f32x4){0.f, 0.f, 0.f, 0.f};

#pragma unroll
  for (int ks = 0; ks < 2; ++ks) {
    bf16x8 bh[4], bl[4];
#pragma unroll
    for (int nt = 0; nt < 4; ++nt) {
      int n_ = ((nth * 4 + nt) * 16) + l15;
      int e = n_ * 4 + ks * 32 + l4 * 8;
      bf16x4 h0 = *reinterpret_cast<const bf16x4*>(xph + e);
      bf16x4 h1 = *reinterpret_cast<const bf16x4*>(xph + e + 4);
      bf16x4 l0 = *reinterpret_cast<const bf16x4*>(xpl + e);
      bf16x4 l1 = *reinterpret_cast<const bf16x4*>(xpl + e + 4);
      bh[nt] = mk8(h0, h1); bl[nt] = mk8(l0, l1);
    }
#pragma unroll
    for (int cs = 0; cs < 2; ++cs)
#pragma unroll
      for (int nt = 0; nt < 4; ++nt) {
        SPMACC(acc1[cs][nt], WA[cs][0][ks], WA[cs][1][ks], bh[nt], bl[nt]);
      }
  }

#pragma unroll
  for (int cs = 0; cs < 2; ++cs)
#pragma unroll
    for (int nt = 0; nt < 4; ++nt) {
      int k = (nth * 4 + nt) * 16 + l15;
      bool kv = (k < 121);
#pragma unroll
      for (int r = 0; r < 4; ++r) {
        int f = mt * 16 + l4 * 4 + r;
        float v = kv ? acc1[cs][nt][r] : 0.f;
        ushort h, l; split_bf(v, h, l);
        int ba = (f << 8) + (k << 1); ba ^= (f & 7) << 4;
        *reinterpret_cast<ushort*>(smem + cs * 32768 + ba) = h;
        *reinterpret_cast<ushort*>(smem + cs * 32768 + 16384 + ba) = l;
        int bt = (k << 7) + (f << 1); bt ^= (k & 7) << 4;
        *reinterpret_cast<ushort*>(smem + 65536 + cs * 32768 + bt) = h;
        *reinterpret_cast<ushort*>(smem + 65536 + cs * 32768 + 16384 + bt) = l;
      }
    }
  __syncthreads();

  // ---- phase 2: QK^T + sigmoid ----
  f32x4 acc2[2][4];  // [nt][rr, ii, ri, ir]
#pragma unroll
  for (int nt = 0; nt < 2; ++nt)
#pragma unroll
    for (int c = 0; c < 4; ++c) acc2[nt][c] = (f32x4){0.f, 0.f, 0.f, 0.f};

#pragma unroll
  for (int ks = 0; ks < 4; ++ks) {
    bf16x8 A_[2][2];
#pragma unroll
    for (int comp = 0; comp < 2; ++comp)
#pragma unroll
      for (int part = 0; part < 2; ++part) {
        int f = mt * 16 + l15;
        int ba = (f << 8) + ((ks * 32 + l4 * 8) << 1); ba ^= (f & 7) << 4;
        A_[comp][part] = *reinterpret_cast<const bf16x8*>(smem + comp * 32768 + part * 16384 + ba);
      }
    bf16x8 B_[2][2][2];
#pragma unroll
    for (int comp = 0; comp < 2; ++comp)
#pragma unroll
      for (int part = 0; part < 2; ++part)
#pragma unroll
        for (int nt = 0; nt < 2; ++nt) {
          int g = (nth * 2 + nt) * 16 + l15;
          int ba = (g << 8) + ((ks * 32 + l4 * 8) << 1); ba ^= (g & 7) << 4;
          B_[comp][part][nt] = *reinterpret_cast<const bf16x8*>(smem + comp * 32768 + part * 16384 + ba);
        }
#pragma unroll
    for (int nt = 0; nt < 2; ++nt) {
      SPMACC(acc2[nt][0], A_[0][0], A_[0][1], B_[0][0][nt], B_[0][1][nt]);
      SPMACC(acc2[nt][1], A_[1][0], A_[1][1], B_[1][0][nt], B_[1][1][nt]);
      SPMACC(acc2[nt][2], A_[0][0], A_[0][1], B_[1][0][nt], B_[1][1][nt]);
      SPMACC(acc2[nt][3], A_[1][0], A_[1][1], B_[0][0][nt], B_[0][1][nt]);
    }
  }
  __syncthreads();

#pragma unroll
  for (int nt = 0; nt < 2; ++nt) {
    int g = (nth * 2 + nt) * 16 + l15;
#pragma unroll
    for (int r = 0; r < 4; ++r) {
      int f = mt * 16 + l4 * 4 + r;
      float qr = acc2[nt][0][r] - acc2[nt][1][r];
      float qi = acc2[nt][2][r] + acc2[nt][3][r];
      float vr = 1.f / (1.f + __expf(-qr));
      float vi = 1.f / (1.f + __expf(-qi));
      int ba = (f << 7) + (g << 1); ba ^= (f & 7) << 4;
      ushort h, l;
      split_bf(vr, h, l);
      *reinterpret_cast<ushort*>(smem + ba) = h;
      *reinterpret_cast<ushort*>(smem + 8192 + ba) = l;
      split_bf(vi, h, l);
      *reinterpret_cast<ushort*>(smem + 16384 + ba) = h;
      *reinterpret_cast<ushort*>(smem + 24576 + ba) = l;
    }
  }
  __syncthreads();

  // ---- phase 3: A = Q @ S ----
  f32x4 acc3[4][3];
#pragma unroll
  for (int nt = 0; nt < 4; ++nt)
#pragma unroll
    for (int c = 0; c < 3; ++c) acc3[nt][c] = (f32x4){0.f, 0.f, 0.f, 0.f};

#pragma unroll
  for (int ks = 0; ks < 2; ++ks) {
    bf16x8 QA[2][2];
#pragma unroll
    for (int comp = 0; comp < 2; ++comp)
#pragma unroll
      for (int part = 0; part < 2; ++part) {
        int f = mt * 16 + l15;
        int ba = (f << 7) + ((ks * 32 + l4 * 8) << 1); ba ^= (f & 7) << 4;
        QA[comp][part] = *reinterpret_cast<const bf16x8*>(smem + comp * 16384 + part * 8192 + ba);
      }
#pragma unroll
    for (int nt = 0; nt < 4; ++nt) {
      int k = (nth * 4 + nt) * 16 + l15;
      int bq = (k << 7) + ((ks * 32 + l4 * 8) << 1); bq ^= (k & 7) << 4;
      bf16x8 Srh = *reinterpret_cast<const bf16x8*>(smem + 65536 + bq);
      bf16x8 Srl = *reinterpret_cast<const bf16x8*>(smem + 81920 + bq);
      bf16x8 Sih = *reinterpret_cast<const bf16x8*>(smem + 98304 + bq);
      bf16x8 Sil = *reinterpret_cast<const bf16x8*>(smem + 114688 + bq);
      SPMACC(acc3[nt][0], QA[0][0], QA[0][1], Srh, Srl);
      SPMACC(acc3[nt][1], QA[1][0], QA[1][1], Sih, Sil);
      SPMACC(acc3[nt][2], QA[0][0], QA[0][1], Sih, Sil);
      SPMACC(acc3[nt][2], QA[1][0], QA[1][1], Srh, Srl);
    }
  }
  __syncthreads();

#pragma unroll
  for (int nt = 0; nt < 4; ++nt) {
    int k = (nth * 4 + nt) * 16 + l15;
#pragma unroll
    for (int r = 0; r < 4; ++r) {
      int f = mt * 16 + l4 * 4 + r;
      float ar = acc3[nt][0][r] - acc3[nt][1][r];
      float ai = acc3[nt][2][r];
      int ba = (f << 8) + (k << 1); ba ^= (f & 7) << 4;
      *reinterpret_cast<ushort*>(smem + ba) = f2bf(ar);
      *reinterpret_cast<ushort*>(smem + 16384 + ba) = f2bf(ai);
    }
  }
  __syncthreads();

  uint4* dst = reinterpret_cast<uint4*>(ap);
  for (int i = tid; i < 2048; i += 512) {
    int comp = i >> 10, rem = i & 1023;
    int f = rem >> 4, q = rem & 15;
    uint4 v = *reinterpret_cast<const uint4*>(
        smem + comp * 16384 + (f << 8) + ((q ^ (f & 7)) << 4));
    dst[((size_t)(b * 64 + n + 32 * comp) * 64) * 16 + rem] = v;
  }
}

// ---------------------------------------------------------------------------
// Kernel 2: transpose a_planar [b][cc][h][w] -> a_nhwc [b][h][w][cc].
// ---------------------------------------------------------------------------
__global__ __launch_bounds__(256) void transpose_k(const ushort* __restrict__ ap,
                                                   ushort* __restrict__ an) {
  __shared__ ushort T[64 * 128];
  const int b = blockIdx.x >> 6, h = blockIdx.x & 63;
  const int tid = threadIdx.x;
#pragma unroll
  for (int it = 0; it < 4; ++it) {
    int i = it * 256 + tid;
    int cc = i >> 4, q = i & 15;
    const uint4* src = reinterpret_cast<const uint4*>(ap) +
                       ((size_t)((b * 64 + cc) * 64 + h) * 16 + q);
    *reinterpret_cast<uint4*>(&T[cc * 128 + q * 8]) = *src;
  }
  __syncthreads();
  const int p = tid >> 1, cc0 = (tid & 1) * 32;
  uint ou[16];
#pragma unroll
  for (int it = 0; it < 16; ++it) {
    uint lo = T[(cc0 + 2 * it) * 128 + p];
    uint hi = T[(cc0 + 2 * it + 1) * 128 + p];
    ou[it] = lo | (hi << 16);
  }
  uint4* dst = reinterpret_cast<uint4*>(an + ((size_t)((b * 64 + h) * 128 + p) * 64 + cc0));
#pragma unroll
  for (int r = 0; r < 4; ++r) dst[r] = make_uint4(ou[4*r], ou[4*r+1], ou[4*r+2], ou[4*r+3]);
}

// ---------------------------------------------------------------------------
// Kernel 3: prep (unchanged).
// ---------------------------------------------------------------------------
__global__ __launch_bounds__(256) void prep_k(
    const float* __restrict__ w0r, const float* __restrict__ w0i,
    const float* __restrict__ b0r, const float* __restrict__ b0i,
    const float* __restrict__ W1r, const float* __restrict__ W1i,
    const float* __restrict__ B1r, const float* __restrict__ B1i,
    const float* __restrict__ W2r, const float* __restrict__ W2i,
    const float* __restrict__ B2r, const float* __restrict__ B2i,
    const float* __restrict__ wl2,
    ushort* __restrict__ AF, ushort* __restrict__ WF, float* __restrict__ BB,
    float* __restrict__ wl2T) {
  const int blk = blockIdx.x, tid = threadIdx.x;
  const float PI32 = 0.0981747704246810387f;

  if (blk == 38) {
    for (int i = tid; i < 121 * 480; i += 256) {
      int k = i / 480, t = i - k * 480;
      wl2T[i] = wl2[t * 121 + k];
    }
    return;
  }
  if (blk == 37) {
    for (int i = tid; i < 16384; i += 256) {
      int j = i & 7, ln = (i >> 3) & 63, mt = (i >> 9) & 3, ks = (i >> 11) & 1;
      int part = (i >> 12) & 1, cs = (i >> 13) & 1;
      int f = mt * 16 + (ln & 15);
      int t = ks * 32 + (ln >> 4) * 8 + j;
      float win = 0.5f * (1.0f - __cosf(PI32 * (float)t));
      int m = (f * t) & 63;
      float sv, cv;
      __sincosf(PI32 * (float)m, &sv, &cv);
      float val = (cs == 0) ? (win * cv * 0.125f) : (-win * sv * 0.125f);
      ushort h = f2bf(val);
      WF[i] = part ? f2bf(val - bf2f_raw(h)) : h;
    }
    return;
  }

  int conv, tap, TT;
  const float *Wr, *Wi;
  if (blk == 0) { conv = 0; tap = 0; TT = 1; Wr = w0r; Wi = w0i; }
  else {
    int q = blk - 1; conv = 1 + q / 9; tap = q - (q / 9) * 9; TT = 9;
    if (conv == 1)      { Wr = W1r;        Wi = W1i; }
    else if (conv == 2) { Wr = W2r;        Wi = W2i; }
    else if (conv == 3) { Wr = W1r + 9216; Wi = W1i + 9216; }
    else                { Wr = W2r + 9216; Wi = W2i + 9216; }
  }
  ushort thi[16], tlo[16];
#pragma unroll
  for (int jj = 0; jj < 16; ++jj) {
    int e = tid * 16 + jj;
    int j = e & 7, lane_e = (e >> 3) & 63, mt = (e >> 9) & 3, ks = (e >> 11) & 1;
    int o  = mt * 16 + (lane_e & 15);
    int cc = ks * 32 + 8 * (lane_e >> 4) + j;
    int ci = cc & 31, ch = cc >> 5, on = o & 31, oh = o >> 5;
    float wr = Wr[(on * 32 + ci) * TT + tap];
    float wi = Wi[(on * 32 + ci) * TT + tap];
    float v = (oh == 0) ? (ch == 0 ? wr : -wi) : (ch == 0 ? wi : wr);
    ushort h = f2bf(v);
    thi[jj] = h;
    tlo[jj] = f2bf(v - bf2f_raw(h));
  }
  ushort* base = AF + conv * 73728 + tap * 8192 + tid * 16;
  uint4* dh = reinterpret_cast<uint4*>(base);
  uint4* dl = reinterpret_cast<uint4*>(base + 4096);
  dh[0] = *reinterpret_cast<uint4*>(&thi[0]);
  dh[1] = *reinterpret_cast<uint4*>(&thi[8]);
  dl[0] = *reinterpret_cast<uint4*>(&tlo[0]);
  dl[1] = *reinterpret_cast<uint4*>(&tlo[8]);

  if (blk == 0) {
    for (int i = tid; i < 320; i += 256) {
      int c = i >> 6, o = i & 63;
      const float *br, *bi;
      if (c == 0)      { br = b0r;      bi = b0i; }
      else if (c == 1) { br = B1r;      bi = B1i; }
      else if (c == 2) { br = B2r;      bi = B2i; }
      else if (c == 3) { br = B1r + 32; bi = B1i + 32; }
      else             { br = B2r + 32; bi = B2i + 32; }
      BB[c * 64 + o] = (o < 32) ? (br[o] - bi[o]) : (br[o - 32] + bi[o - 32]);
    }
  }
}

// ---------------------------------------------------------------------------
// Conv: 3 static LDS row buffers [128 w][64 cc] bf16 (16KB each, swizzled
// byte ^= (w&7)<<4), one barrier. A-frag ping-pong pipeline (hi/lo groups).
// Wave: M-tiles {mtb, mtb+2} (o and o+32 = real/imag pair), N-tiles ntb..+3.
// ---------------------------------------------------------------------------
template <int NT>
__device__ __forceinline__ void run_taps(const char* __restrict__ smem,
    const ushort* __restrict__ afrag,
    const int (&bufs)[NT], const int (&dxo)[NT], const int (&aoffs)[NT],
    int ntb, int mtb, int l15, int l4, int lane, f32x4 acc[2][4]) {
  const ushort* Ab = afrag + lane * 8;
  bf16x8 G0[4], G1[4];  // [ks*2+mi]: hi / lo parts of current tap
  {
    const ushort* At = Ab + aoffs[0] * 8192;
#pragma unroll
    for (int ks = 0; ks < 2; ++ks)
#pragma unroll
      for (int mi = 0; mi < 2; ++mi) {
        G0[ks * 2 + mi] = *reinterpret_cast<const bf16x8*>(At + ks * 2048 + (mtb + 2 * mi) * 512);
        G1[ks * 2 + mi] = *reinterpret_cast<const bf16x8*>(At + 4096 + ks * 2048 + (mtb + 2 * mi) * 512);
      }
  }
#pragma unroll
  for (int t = 0; t < NT; ++t) {
    bf16x8 bv[2][4];  // [ks][nt], shared by hi and lo parts
#pragma unroll
    for (int ks = 0; ks < 2; ++ks)
#pragma unroll
      for (int nt = 0; nt < 4; ++nt) {
        int w = (ntb + nt) * 16 + l15 + dxo[t];
        bool val = ((unsigned)w < 128u);
        int wc = val ? w : 0;
        int byt = bufs[t] * 16384 + wc * 128 + ks * 64 + l4 * 16;
        byt ^= (wc & 7) << 4;
        bf16x8 tt = *reinterpret_cast<const bf16x8*>(smem + byt);
        bv[ks][nt] = val ? tt : (bf16x8){0, 0, 0, 0, 0, 0, 0, 0};
      }
    __builtin_amdgcn_s_setprio(1);
#pragma unroll
    for (int ks = 0; ks < 2; ++ks)
#pragma unroll
      for (int nt = 0; nt < 4; ++nt) {
        acc[0][nt] = MFMA16(G0[ks * 2 + 0], bv[ks][nt], acc[0][nt]);
        acc[1][nt] = MFMA16(G0[ks * 2 + 1], bv[ks][nt], acc[1][nt]);
      }
    __builtin_amdgcn_s_setprio(0);
    if (t + 1 < NT) {  // prefetch hi(t+1) while lo(t) computes
      const ushort* At = Ab + aoffs[t + 1 < NT ? t + 1 : 0] * 8192;
#pragma unroll
      for (int ks = 0; ks < 2; ++ks)
#pragma unroll
        for (int mi = 0; mi < 2; ++mi)
          G0[ks * 2 + mi] = *reinterpret_cast<const bf16x8*>(At + ks * 2048 + (mtb + 2 * mi) * 512);
    }
    __builtin_amdgcn_s_setprio(1);
#pragma unroll
    for (int ks = 0; ks < 2; ++ks)
#pragma unroll
      for (int nt = 0; nt < 4; ++nt) {
        acc[0][nt] = MFMA16(G1[ks * 2 + 0], bv[ks][nt], acc[0][nt]);
        acc[1][nt] = MFMA16(G1[ks * 2 + 1], bv[ks][nt], acc[1][nt]);
      }
    __builtin_amdgcn_s_setprio(0);
    if (t + 1 < NT) {  // prefetch lo(t+1); wait covered by next tap's hi
      const ushort* At = Ab + aoffs[t + 1 < NT ? t + 1 : 0] * 8192;
#pragma unroll
      for (int ks = 0; ks < 2; ++ks)
#pragma unroll
        for (int mi = 0; mi < 2; ++mi)
          G1[ks * 2 + mi] = *reinterpret_cast<const bf16x8*>(At + 4096 + ks * 2048 + (mtb + 2 * mi) * 512);
    }
  }
}

template <int ROWS>
__device__ __forceinline__ void conv_body(char* smem,
    const ushort* __restrict__ xin, ushort* __restrict__ tout,
    const ushort* __restrict__ afrag, const float* __restrict__ bb,
    const float* __restrict__ wl0, float* __restrict__ csum,
    int d, int b, int h, int mode, int tid) {
  const int wave = tid >> 6, lane = tid & 63;
  const int mtb = wave & 1;
  const int ntb = (wave >> 1) * 4;
  const int l15 = lane & 15, l4 = lane >> 4;

  uint4 sa[4], sb[4];
#define LOADR(st, hh)                                                          \
  {                                                                            \
    const uint4* src = reinterpret_cast<const uint4*>(xin) +                   \
                       ((size_t)(b * 64 + (hh)) << 10);                        \
    st[0] = src[tid]; st[1] = src[tid + 256];                                  \
    st[2] = src[tid + 512]; st[3] = src[tid + 768];                            \
  }
#define WRITER(st, buf)                                                        \
  {                                                                            \
    _Pragma("unroll")                                                          \
    for (int it = 0; it < 4; ++it) {                                           \
      int i = it * 256 + tid;                                                  \
      int w = i >> 3, q = i & 7;                                               \
      int byt = (buf) * 16384 + w * 128 + q * 16;                              \
      byt ^= (w & 7) << 4;                                                     \
      *reinterpret_cast<uint4*>(smem + byt) = st[it];                          \
    }                                                                          \
  }

  f32x4 acc[2][4];
#pragma unroll
  for (int mi = 0; mi < 2; ++mi)
#pragma unroll
    for (int nt = 0; nt < 4; ++nt) acc[mi][nt] = (f32x4){0.f, 0.f, 0.f, 0.f};

  if constexpr (ROWS == 1) {
    LOADR(sa, h);
    WRITER(sa, 0);
    __syncthreads();
    const int B1_[1] = {0}, D1_[1] = {0}, A1_[1] = {0};
    run_taps<1>(smem, afrag, B1_, D1_, A1_, ntb, mtb, l15, l4, lane, acc);
  } else {
    const int hm = h - d, hp = h + d;
    const bool v0 = (hm >= 0), v2 = (hp < 64);
    if (v0) LOADR(sa, hm);
    LOADR(sb, h);
    if (v0) WRITER(sa, 0);
    if (v2) LOADR(sa, hp);
    WRITER(sb, 1);
    if (v2) WRITER(sa, 2);
    __syncthreads();
    if (v0 && v2) {
      const int B_[9] = {0, 0, 0, 1, 1, 1, 2, 2, 2};
      const int A_[9] = {0, 1, 2, 3, 4, 5, 6, 7, 8};
      const int D_[9] = {-d, 0, d, -d, 0, d, -d, 0, d};
      run_taps<9>(smem, afrag, B_, D_, A_, ntb, mtb, l15, l4, lane, acc);
    } else if (v0) {
      const int B_[6] = {0, 0, 0, 1, 1, 1};
      const int A_[6] = {0, 1, 2, 3, 4, 5};
      const int D_[6] = {-d, 0, d, -d, 0, d};
      run_taps<6>(smem, afrag, B_, D_, A_, ntb, mtb, l15, l4, lane, acc);
    } else {
      const int B_[6] = {1, 1, 1, 2, 2, 2};
      const int A_[6] = {3, 4, 5, 6, 7, 8};
      const int D_[6] = {-d, 0, d, -d, 0, d};
      run_taps<6>(smem, afrag, B_, D_, A_, ntb, mtb, l15, l4, lane, acc);
    }
  }
#undef LOADR
#undef WRITER

  if (mode == 2) {
    __syncthreads();                       // row buffers free -> bounce
    uint* Lb = reinterpret_cast<uint*>(smem);  // [32 o-pairs][132]
#pragma unroll
    for (int mi = 0; mi < 2; ++mi) {
#pragma unroll
      for (int rp = 0; rp < 2; ++rp) {
        int o = (mtb + 2 * mi) * 16 + l4 * 4 + rp * 2;
        float b0 = bb[o], b1 = bb[o + 1];
#pragma unroll
        for (int nt = 0; nt < 4; ++nt) {
          int w = (ntb + nt) * 16 + l15;
          uint pk = (uint)f2bf(acc[mi][nt][rp * 2] + b0) |
                    ((uint)f2bf(acc[mi][nt][rp * 2 + 1] + b1) << 16);
          Lb[(o >> 1) * 132 + w] = pk;
        }
      }
    }
    __syncthreads();
    const int p = tid >> 1, cph = (tid & 1) * 16;  // cc-pair base
    const bool val = (p < 121);
    uint ou[16];
#pragma unroll
    for (int it = 0; it < 16; ++it)
      ou[it] = val ? Lb[(cph + it) * 132 + p] : 0u;
    uint4* dst = reinterpret_cast<uint4*>(
        tout + ((size_t)((b * 64 + h) * 128 + p) * 64 + cph * 2));
#pragma unroll
    for (int r = 0; r < 4; ++r) dst[r] = make_uint4(ou[4*r], ou[4*r+1], ou[4*r+2], ou[4*r+3]);
  } else {
    const float w00 = wl0[0], w01 = wl0[1];
    float br_[4], bi_[4];
#pragma unroll
    for (int r = 0; r < 4; ++r) {
      int n = mtb * 16 + l4 * 4 + r;
      br_[r] = bb[n]; bi_[r] = bb[n + 32];
    }
#pragma unroll
    for (int nt = 0; nt < 4; ++nt) {
      int w = (ntb + nt) * 16 + l15;
      if (w < 121) {
#pragma unroll
        for (int r = 0; r < 4; ++r) {
          int n = mtb * 16 + l4 * 4 + r;
          float rr = acc[0][nt][r] + br_[r];
          float im = acc[1][nt][r] + bi_[r];
          float v = (fmaxf(rr, 0.f) * w00 + fmaxf(im, 0.f) * w01) * (1.f / 3.f);
          float* p = csum + ((size_t)(b * 32 + n) * 64 + h) * 121 + w;
          if (mode == 1) v += *p;
          *p = v;
        }
      }
    }
  }
}

// D1: x=bid&7 (XCD), j=bid>>3: role=j%3, wg=(x<<9)|(j/3). The 3 roles of one
// (b,h) run back-to-back on the SAME XCD -> L2 serves an's reuse.
__global__ __launch_bounds__(256, 3) void convD1_k(
    const ushort* __restrict__ an, ushort* __restrict__ t1, ushort* __restrict__ t2,
    const ushort* __restrict__ AF, const float* __restrict__ BB,
    const float* __restrict__ wl0, float* __restrict__ csumA) {
  __shared__ __align__(16) char smem[49152];
  const int x = blockIdx.x & 7, j = blockIdx.x >> 3;
  const int role = j % 3, local = j / 3;
  const int wg = (x << 9) | local;
  const int b = wg >> 6, h = wg & 63;
  const int tid = threadIdx.x;
  if (role == 0)
    conv_body<1>(smem, an, nullptr, AF, BB, wl0, csumA, 1, b, h, 0, tid);
  else if (role == 1)
    conv_body<3>(smem, an, t1, AF + 1 * 73728, BB + 64, wl0, nullptr, 1, b, h, 2, tid);
  else
    conv_body<3>(smem, an, t2, AF + 3 * 73728, BB + 192, wl0, nullptr, 2, b, h, 2, tid);
}

// D2: x=bid&7, j=bid>>3: role=j&1, wg=(x<<9)|(j>>1).
__global__ __launch_bounds__(256, 3) void convD2_k(
    const ushort* __restrict__ t1, const ushort* __restrict__ t2,
    const ushort* __restrict__ AF, const float* __restrict__ BB,
    const float* __restrict__ wl0, float* __restrict__ csumA,
    float* __restrict__ csumB) {
  __shared__ __align__(16) char smem[49152];
  const int x = blockIdx.x & 7, j = blockIdx.x >> 3;
  const int role = j & 1, local = j >> 1;
  const int wg = (x << 9) | local;
  const int b = wg >> 6, h = wg & 63;
  const int tid = threadIdx.x;
  if (role == 0)
    conv_body<3>(smem, t1, nullptr, AF + 2 * 73728, BB + 128, wl0, csumA, 1, b, h, 1, tid);
  else
    conv_body<3>(smem, t2, nullptr, AF + 4 * 73728, BB + 256, wl0, csumB, 2, b, h, 0, tid);
}

// ---------------------------------------------------------------------------
// Kernel 5: epilogue. h[k] = mean_f(csumA+csumB) + b_l0 ; y = h @ w_l2T + b_l2
// ---------------------------------------------------------------------------
__global__ __launch_bounds__(256) void epi_k(const float* __restrict__ csumA,
    const float* __restrict__ csumB,
    const float* __restrict__ bl0, const float* __restrict__ wl2T,
    const float* __restrict__ bl2, float* __restrict__ out) {
  const int b = blockIdx.x >> 5, n = blockIdx.x & 31;
  __shared__ float sh[121];
  const int tid = threadIdx.x;
  const float* baseA = csumA + (size_t)(b * 32 + n) * 64 * 121;
  const float* baseB = csumB + (size_t)(b * 32 + n) * 64 * 121;
  for (int k = tid; k < 121; k += 256) {
    float s = 0.f;
#pragma unroll 8
    for (int f = 0; f < 64; ++f) s += baseA[f * 121 + k] + baseB[f * 121 + k];
    sh[k] = s * (1.f / 64.f) + bl0[0];
  }
  __syncthreads();
  for (int t = tid; t < 480; t += 256) {
    float acc = bl2[t];
#pragma unroll 8
    for (int k = 0; k < 121; ++k) acc = fmaf(sh[k], wl2T[k * 480 + t], acc);
    out[(b * 480 + t) * 32 + n] = acc;
  }
}

// ---------------------------------------------------------------------------
extern "C" void kernel_launch(void* const* d_in, const int* in_sizes, int n_in,
                              void* d_out, int out_size, void* d_ws, size_t ws_size,
                              hipStream_t stream) {
  const float* x   = (const float*)d_in[0];
  const float* w0r = (const float*)d_in[1];
  const float* w0i = (const float*)d_in[2];
  const float* b0r = (const float*)d_in[3];
  const float* b0i = (const float*)d_in[4];
  const float* W1r = (const float*)d_in[5];
  const float* W1i = (const float*)d_in[6];
  const float* B1r = (const float*)d_in[7];
  const float* B1i = (const float*)d_in[8];
  const float* W2r = (const float*)d_in[9];
  const float* W2i = (const float*)d_in[10];
  const float* B2r = (const float*)d_in[11];
  const float* B2i = (const float*)d_in[12];
  const float* wl0 = (const float*)d_in[13];
  const float* bl0 = (const float*)d_in[14];
  const float* wl2 = (const float*)d_in[15];
  const float* bl2 = (const float*)d_in[16];

  char* ws = (char*)d_ws;
  const size_t MB64 = (size_t)64 << 20;
  ushort* ap    = (ushort*)ws;                       // a_planar -> t2 later
  ushort* t2    = (ushort*)ws;
  ushort* an    = (ushort*)(ws + MB64);              // a_nhwc -> csumB later
  float*  csumB = (float*)(ws + MB64);
  ushort* t1    = (ushort*)(ws + 2 * MB64);
  float*  csumA = (float*)(ws + 3 * MB64);           // [b][32][64][121] fp32
  const size_t CSZ = (size_t)64 * 32 * 64 * 121 * 4; // 63,438,848 B
  ushort* AF   = (ushort*)(ws + 3 * MB64 + CSZ);     // 737,280 B
  ushort* WFp  = AF + 5 * 73728;                     // 32,768 B
  float*  BB   = (float*)(WFp + 16384);              // 1,280 B
  float*  wl2T = BB + 320;                           // 232,320 B
  float*  out  = (float*)d_out;

  hipLaunchKernelGGL(prep_k, dim3(39), dim3(256), 0, stream,
                     w0r, w0i, b0r, b0i, W1r, W1i, B1r, B1i, W2r, W2i, B2r, B2i,
                     wl2, AF, WFp, BB, wl2T);
  hipLaunchKernelGGL(stft_mfma_k, dim3(2048), dim3(512), 0, stream, x, WFp, ap);
  hipLaunchKernelGGL(transpose_k, dim3(4096), dim3(256), 0, stream, ap, an);
  // D1: conv0 -> csumA ; conv1(d=1) -> t1 ; conv1(d=2) -> t2 (overwrites ap)
  hipLaunchKernelGGL(convD1_k, dim3(12288), dim3(256), 0, stream,
                     an, t1, t2, AF, BB, wl0, csumA);
  // D2: conv2(d=1) += csumA ; conv2(d=2) -> csumB (overwrites an)
  hipLaunchKernelGGL(convD2_k, dim3(8192), dim3(256), 0, stream,
                     t1, t2, AF, BB, wl0, csumA, csumB);
  hipLaunchKernelGGL(epi_k, dim3(2048), dim3(256), 0, stream,
                     csumA, csumB, bl0, wl2T, bl2, out);
}